// Round 2
// baseline (309.499 us; speedup 1.0000x reference)
//
#include <hip/hip_runtime.h>
#include <math.h>

// Shapes (fixed by the reference)
#define DXc   16
#define MRc   64
#define MBARc 256
#define NTc   9
#define DYc   8
#define HXc   1024
#define EXc   512
#define HRc   512
#define HBc   2048
#define GOUTc 64
#define TOTc  2049   // (NT-1)*MBAR + 1

using bf16x8 = __attribute__((ext_vector_type(8))) short;
using f32x4  = __attribute__((ext_vector_type(4))) float;

typedef unsigned int u32;
typedef u32 __attribute__((address_space(1))) gbl_u32;
typedef u32 __attribute__((address_space(3))) lds_u32;

__device__ __forceinline__ float fast_tanh(float x){
    float e = __expf(2.0f * x);
    return 1.0f - 2.0f / (e + 1.0f);
}

// fp32 -> bf16 round-to-nearest-even (bit pattern in a short)
__device__ __forceinline__ short f2bf(float f){
    unsigned u = __builtin_bit_cast(unsigned, f);
    u = (u + 0x7FFFu + ((u >> 16) & 1u)) >> 16;
    return (short)u;
}

// async global->LDS: each lane loads 16 B from g + lane*16; LDS dest = base + lane*16
__device__ __forceinline__ void gld_lds16(const short* g, short* l){
    __builtin_amdgcn_global_load_lds((const gbl_u32*)g, (lds_u32*)l, 16, 0, 0);
}

// ---------------- prep: SW + packs (Wx2a A-layout, Wb1p B-layout) + XW/T1 + wrow + inits ----------------
// grid 4673 x 256
__global__ void prep_kernel(const float* __restrict__ stoich, const float* __restrict__ Wx1,
                            const float* __restrict__ Wx2, const float* __restrict__ Wb1,
                            const float* __restrict__ X, const float* __restrict__ R,
                            const float* __restrict__ bx1, const float* __restrict__ bx2,
                            const int* kpptr, const int* qpptr,
                            float* __restrict__ SW, short* __restrict__ Wx2a,
                            short* __restrict__ Wb1p, float* __restrict__ XW,
                            float* __restrict__ T1, float* __restrict__ wrow,
                            float* __restrict__ hb0, float* __restrict__ dacc,
                            float* __restrict__ outz, float* __restrict__ eXb,
                            float* __restrict__ Z2Bacc, int* __restrict__ cnt){
    int b = blockIdx.x, tid = threadIdx.x;
    if (b < 256){
        // SW[j][c] = stoich[:,j] @ Wx1
        int idx = b * 256 + tid;
        int j = idx >> 10, c = idx & 1023;
        float acc = 0.f;
        #pragma unroll
        for (int d = 0; d < DXc; ++d) acc += stoich[d * MRc + j] * Wx1[d * HXc + c];
        SW[idx] = acc;
    } else if (b < 512){
        // pack Wx2 (1024x512) into MFMA A-fragment order (M=c rows, K=e), KTOT=16
        size_t grp = (size_t)(b - 256) * 256 + tid;    // 65536 groups
        int lane = grp & 63;
        size_t t2 = grp >> 6;
        int kt = t2 & 15, mt = t2 >> 4;                // mt 0..63
        int c  = mt * 16 + (lane & 15);
        int e0 = kt * 32 + ((lane >> 4) << 3);
        short o8[8];
        #pragma unroll
        for (int jj = 0; jj < 8; ++jj) o8[jj] = f2bf(Wx2[(size_t)c * EXc + e0 + jj]);
        *(bf16x8*)(Wx2a + grp * 8) = *(bf16x8*)o8;
    } else if (b < 1024){
        // pack Wb1 rows 1..512 (512x2048) into B-fragment order, KTOT=16
        size_t grp = (size_t)(b - 512) * 256 + tid;
        int lane = grp & 63;
        size_t t2 = grp >> 6;
        int kt = t2 & 15, nt = t2 >> 4;
        int n  = nt * 16 + (lane & 15);
        int k0 = kt * 32 + ((lane >> 4) << 3);
        short o8[8];
        #pragma unroll
        for (int jj = 0; jj < 8; ++jj) o8[jj] = f2bf(Wb1[(size_t)(1 + k0 + jj) * HBc + n]);
        *(bf16x8*)(Wb1p + grp * 8) = *(bf16x8*)o8;
    } else if (b < 2048){
        // XW = Xbase@Wx1 + bx1 ; T1 = tanh(XW)
        int idx = (b - 1024) * 256 + tid;
        int m = idx >> 10, c = idx & 1023;
        int base = kpptr[0] * MBARc;
        const float* xr = X + ((size_t)qpptr[0] * TOTc + base + m) * DXc;
        float acc = bx1[c];
        #pragma unroll
        for (int d = 0; d < DXc; ++d) acc += xr[d] * Wx1[d * HXc + c];
        XW[idx] = acc;
        T1[idx] = fast_tanh(acc);
    } else if (b < 2112){
        // wrow[j*256+m] = valid(j,m) * R_delta
        int j = b - 2048, m = tid;
        int base = kpptr[0] * MBARc;
        int qp = qpptr[0];
        const float* xr = X + ((size_t)qp * TOTc + base + m) * DXc;
        bool valid = true;
        #pragma unroll
        for (int d = 0; d < DXc; ++d) valid = valid && (xr[d] + stoich[d * MRc + j] >= 0.f);
        size_t rb = (size_t)qp * TOTc * MRc;
        float rd = R[rb + (size_t)(base + 1 + m) * MRc + j] - R[rb + (size_t)(base + m) * MRc + j];
        wrow[j * MBARc + m] = valid ? rd : 0.f;
    } else if (b == 2112){
        hb0[tid] = 0.f; hb0[tid + 256] = 0.f;
        #pragma unroll
        for (int l = 0; l < 8; ++l) dacc[tid + l * 256] = 0.f;
        if (tid < GOUTc) outz[tid] = 0.f;
        if (tid == 0) cnt[0] = 0;
    } else if (b < 2625){
        // eXb init = bx2 (broadcast per row); 512 blocks, 131072 elems
        int idx = (b - 2113) * 256 + tid;
        eXb[idx] = bx2[idx & 511];
    } else {
        // Z2Bacc = 0; 2048 blocks, 524288 elems
        Z2Bacc[(size_t)(b - 2625) * 256 + tid] = 0.f;
    }
}

// ---- MFMA helpers (4x4 grid, used by w12) ----
#define MMGRID(aa, bb) {                                                       \
    _Pragma("unroll") for (int i_ = 0; i_ < 4; ++i_)                           \
        _Pragma("unroll") for (int j_ = 0; j_ < 4; ++j_)                       \
            acc[i_][j_] = __builtin_amdgcn_mfma_f32_16x16x32_bf16(aa[i_], bb[j_], acc[i_][j_], 0, 0, 0); }

// stage BK=32 (1 kt): 8 A-chunks + 8 B-chunks of 1 KB; wave w stages 4 chunks
__device__ __forceinline__ void stage32(const short* __restrict__ Ap, const short* __restrict__ Bp,
                                        short* As, short* Bs,
                                        int at0, int bt0, int s, int KTOT, int wave, int lane){
    #pragma unroll
    for (int c = 0; c < 4; ++c){
        int ci = wave * 4 + c;            // 0..15
        int half = ci >> 3;               // 0 = A, 1 = B
        int t    = ci & 7;
        const short* src = half ? (Bp + ((size_t)(bt0 + t) * KTOT + s) * 512 + lane * 8)
                                : (Ap + ((size_t)(at0 + t) * KTOT + s) * 512 + lane * 8);
        short* dst = (half ? Bs : As) + t * 512;
        gld_lds16(src, dst);
    }
}

// compute one stage (1 kt x 16 MFMA per wave) from LDS
#define STAGE_COMPUTE(As, Bs) {                                                       \
    bf16x8 af[4], bfr[4];                                                             \
    _Pragma("unroll") for (int i_ = 0; i_ < 4; ++i_)                                  \
        af[i_] = *(const bf16x8*)((As) + ((wm * 4 + i_) * 512) + lane * 8);           \
    _Pragma("unroll") for (int j_ = 0; j_ < 4; ++j_)                                  \
        bfr[j_] = *(const bf16x8*)((Bs) + ((wn * 4 + j_) * 512) + lane * 8);          \
    MMGRID(af, bfr); }

// ---------------- fused rnn+cY / w12 / act_delta / exbase (independent works, one dispatch) ----------------
// blocks [0,8):      RNN (8 steps, agent-scope atomic sync) + cY  [hidden under the throughput blocks]
// blocks [8,136):    w12 = Wx2bf @ Wb1midbf -> W12p (B-layout for gemm_big)
// blocks [136,8328): act_delta -> A1p
// blocks [8328,8840): exbase split-K -> eXb (+= T1 @ Wx2)
__global__ __launch_bounds__(256) void w12_act_ex_kernel(
    const short* __restrict__ Wx2a, const short* __restrict__ Wb1p,
    short* __restrict__ W12p,
    const float* __restrict__ XW, const float* __restrict__ T1,
    const float* __restrict__ SW, short* __restrict__ A1p,
    const float* __restrict__ Wx2, float* __restrict__ eXb,
    const float* __restrict__ Y, const float* __restrict__ Wih,
    const float* __restrict__ Whh, const float* __restrict__ bh,
    const float* __restrict__ Wb1, const float* __restrict__ bb1,
    const int* kptr, const int* qptr,
    float* __restrict__ hb0, float* __restrict__ hb1,
    int* __restrict__ cnt, float* __restrict__ cY){
    __shared__ __align__(16) short Asb[2][4096];
    __shared__ __align__(16) short Bsb[2][4096];
    int b = blockIdx.x, tid = threadIdx.x;
    if (b < 8){
        // ---- RNN: 8 blocks co-resident (first-dispatched), cross-block sync via cnt ----
        __shared__ float hs[HRc];
        __shared__ float psum[4][64];
        int o = tid & 63, seg = tid >> 6;          // 4 segs x 128 k
        int out = b * 64 + o;
        int k = kptr[0], q = qptr[0];
        hs[tid] = 0.f; hs[tid + 256] = 0.f;
        __syncthreads();
        for (int s = 0; s < 8; ++s){
            float* dst = (s & 1) ? hb0 : hb1;
            if (s > 0){
                const float* src = (s & 1) ? hb1 : hb0;
                if (tid == 0){
                    int guard = 0;
                    while (__hip_atomic_load(cnt, __ATOMIC_ACQUIRE, __HIP_MEMORY_SCOPE_AGENT) < 8 * s
                           && ++guard < (1 << 26)) {}
                }
                __syncthreads();
                hs[tid]       = __hip_atomic_load(src + tid,       __ATOMIC_RELAXED, __HIP_MEMORY_SCOPE_AGENT);
                hs[tid + 256] = __hip_atomic_load(src + tid + 256, __ATOMIC_RELAXED, __HIP_MEMORY_SCOPE_AGENT);
                __syncthreads();
            }
            int t = k + 1 + s;
            if (t < NTc){
                int k0 = seg * 128;
                float a0 = 0.f, a1 = 0.f, a2 = 0.f, a3 = 0.f;
                #pragma unroll 4
                for (int kk = 0; kk < 128; kk += 4){
                    a0 += hs[k0 + kk + 0] * Whh[(size_t)(k0 + kk + 0) * HRc + out];
                    a1 += hs[k0 + kk + 1] * Whh[(size_t)(k0 + kk + 1) * HRc + out];
                    a2 += hs[k0 + kk + 2] * Whh[(size_t)(k0 + kk + 2) * HRc + out];
                    a3 += hs[k0 + kk + 3] * Whh[(size_t)(k0 + kk + 3) * HRc + out];
                }
                psum[seg][o] = (a0 + a1) + (a2 + a3);
                __syncthreads();
                if (seg == 0){
                    float a = psum[0][o] + psum[1][o] + psum[2][o] + psum[3][o];
                    const float* y = Y + (q * NTc + t) * DYc;
                    float z = bh[out];
                    #pragma unroll
                    for (int d = 0; d < DYc; ++d) z += y[d] * Wih[d * HRc + out];
                    __hip_atomic_store(dst + out, fast_tanh(z + a), __ATOMIC_RELEASE, __HIP_MEMORY_SCOPE_AGENT);
                }
                __syncthreads();
            } else {
                if (seg == 0)
                    __hip_atomic_store(dst + out, hs[out], __ATOMIC_RELEASE, __HIP_MEMORY_SCOPE_AGENT);
                __syncthreads();
            }
            if (tid == 0)
                __hip_atomic_fetch_add(cnt, 1, __ATOMIC_RELEASE, __HIP_MEMORY_SCOPE_AGENT);
        }
        // ---- cY phase: final eY is in hb0 ----
        if (tid == 0){
            int guard = 0;
            while (__hip_atomic_load(cnt, __ATOMIC_ACQUIRE, __HIP_MEMORY_SCOPE_AGENT) < 64
                   && ++guard < (1 << 26)) {}
        }
        __syncthreads();
        hs[tid]       = __hip_atomic_load(hb0 + tid,       __ATOMIC_RELAXED, __HIP_MEMORY_SCOPE_AGENT);
        hs[tid + 256] = __hip_atomic_load(hb0 + tid + 256, __ATOMIC_RELAXED, __HIP_MEMORY_SCOPE_AGENT);
        __syncthreads();
        int h = b * 256 + tid;
        float acc = 0.f;
        #pragma unroll 4
        for (int e = 0; e < 512; ++e)
            acc += hs[e] * Wb1[(size_t)(1 + EXc + e) * HBc + h];
        cY[h] = bb1[h] + acc;
    } else if (b < 136){
        // ---- w12: 128x128 tiles, K=512 (S=16) ----
        const int KTOT = 16, S = 16;
        int bw = b - 8;
        int wave = tid >> 6, lane = tid & 63;
        int wm = wave >> 1, wn = wave & 1;
        int bx = bw & 15, by = bw >> 4;
        int quad = lane >> 4, llo = lane & 15;
        f32x4 acc[4][4];
        #pragma unroll
        for (int i = 0; i < 4; ++i)
            #pragma unroll
            for (int j = 0; j < 4; ++j) acc[i][j] = (f32x4){0.f, 0.f, 0.f, 0.f};
        stage32(Wx2a, Wb1p, Asb[0], Bsb[0], by * 8, bx * 8, 0, KTOT, wave, lane);
        for (int s = 0; s < S; ++s){
            int buf = s & 1;
            __syncthreads();
            if (s + 1 < S)
                stage32(Wx2a, Wb1p, Asb[buf ^ 1], Bsb[buf ^ 1], by * 8, bx * 8, s + 1, KTOT, wave, lane);
            STAGE_COMPUTE(Asb[buf], Bsb[buf]);
        }
        // write W12[c][h] into gemm_big's B layout: chunk = [h>>8][c>>6][((h>>4)&15)*2 + ((c>>5)&1)],
        // lane = ((c>>3)&3)*16 + (h&15), elem = c&7
        #pragma unroll
        for (int j = 0; j < 4; ++j){
            int h = bx * 128 + wn * 64 + j * 16 + llo;
            #pragma unroll
            for (int i = 0; i < 4; ++i){
                #pragma unroll
                for (int r = 0; r < 4; ++r){
                    int c = by * 128 + wm * 64 + i * 16 + quad * 4 + r;
                    size_t idx = ((((size_t)(h >> 8) * 16 + (c >> 6)) * 32)
                                  + ((h >> 4) & 15) * 2 + ((c >> 5) & 1)) * 512
                               + (size_t)(((c >> 3) & 3) * 16 + (h & 15)) * 8 + (c & 7);
                    W12p[idx] = f2bf(acc[i][j][r]);
                }
            }
        }
    } else if (b < 8328){
        // ---- act_delta: A1p = bf16(tanh(XW+SW[j]) - T1), packed for gemm_big staging ----
        // layout: t2 = j*512 + kt*32 + mt*2 + kk ; value at m=j*256+mt*16+(lane&15),
        //         k = kt*64 + kk*32 + (lane>>4)*8 + e
        size_t grp = (size_t)(b - 136) * 256 + tid;  // 2,097,152 groups
        int lane = (int)(grp & 63);
        size_t t2 = grp >> 6;
        int kk = (int)(t2 & 1);
        int mt = (int)((t2 >> 1) & 15);
        int kt = (int)((t2 >> 5) & 15);
        int j  = (int)(t2 >> 9);             // 0..63 (= 256-row slab = reaction index)
        int mloc = mt * 16 + (lane & 15);    // 0..255
        int c0 = kt * 64 + kk * 32 + ((lane >> 4) << 3);
        const float* xwr = XW + (size_t)mloc * HXc + c0;
        const float* t1r = T1 + (size_t)mloc * HXc + c0;
        const float* swr = SW + (size_t)j * HXc + c0;
        short o8[8];
        #pragma unroll
        for (int i = 0; i < 8; ++i)
            o8[i] = f2bf(fast_tanh(xwr[i] + swr[i]) - t1r[i]);
        *(bf16x8*)(A1p + grp * 8) = *(bf16x8*)o8;
    } else {
        // ---- exbase split-K: eXb += T1 @ Wx2 (eXb pre-init to bx2) ----
        __shared__ float t1s[8 * 128];
        int bb = b - 8328;                   // 0..511
        int mg = bb & 31, eh = (bb >> 5) & 1, kq = bb >> 6;
        int m0 = mg * 8, e = eh * 256 + tid, k0 = kq * 128;
        #pragma unroll
        for (int l = 0; l < 4; ++l){
            int idx = tid + l * 256;
            t1s[idx] = T1[(size_t)(m0 + (idx >> 7)) * HXc + k0 + (idx & 127)];
        }
        __syncthreads();
        float acc[8] = {};
        #pragma unroll 4
        for (int kk = 0; kk < 128; ++kk){
            float wv = Wx2[(size_t)(k0 + kk) * EXc + e];
            #pragma unroll
            for (int mm = 0; mm < 8; ++mm) acc[mm] += t1s[mm * 128 + kk] * wv;
        }
        #pragma unroll
        for (int mm = 0; mm < 8; ++mm)
            atomicAdd(&eXb[(size_t)(m0 + mm) * EXc + e], acc[mm]);
    }
}

// ---------------- z2acc split-K: Z2Bacc += eXb @ Wb1[1:513] ----------------
__global__ __launch_bounds__(256) void z2acc_kernel(const float* __restrict__ eXb,
                                                    const float* __restrict__ Wb1,
                                                    float* __restrict__ Z2Bacc){
    __shared__ float exs[8 * 256];
    int b = blockIdx.x, tid = threadIdx.x;
    int mg = b & 31, hh = (b >> 5) & 7, kq = b >> 8;
    int m0 = mg * 8, h = hh * 256 + tid, k0 = kq * 256;
    #pragma unroll
    for (int l = 0; l < 8; ++l){
        int idx = tid + l * 256;
        exs[idx] = eXb[(size_t)(m0 + (idx >> 8)) * EXc + k0 + (idx & 255)];
    }
    __syncthreads();
    float acc[8] = {};
    #pragma unroll 4
    for (int kk = 0; kk < 256; ++kk){
        float wv = Wb1[(size_t)(1 + k0 + kk) * HBc + h];
        #pragma unroll
        for (int mm = 0; mm < 8; ++mm) acc[mm] += exs[mm * 256 + kk] * wv;
    }
    #pragma unroll
    for (int mm = 0; mm < 8; ++mm)
        atomicAdd(&Z2Bacc[(size_t)(m0 + mm) * HBc + h], acc[mm]);
}

// ---------------- tb: TB = tanh(Z2Bacc + (tk+tau_m)*Wb1[0] + cY) ----------------
__global__ void tb_kernel(const float* __restrict__ Z2Bacc, const float* __restrict__ Wb1,
                          const float* __restrict__ cY, const float* __restrict__ times_t,
                          const float* __restrict__ times_tau, const int* kptr,
                          float* __restrict__ TB){
    int b = blockIdx.x, tid = threadIdx.x;
    int m = b >> 3, h = (b & 7) * 256 + tid;
    float tk = times_t[kptr[0]];
    size_t idx = (size_t)m * HBc + h;
    float z = Z2Bacc[idx] + (tk + times_tau[m]) * Wb1[h] + cY[h];
    TB[idx] = fast_tanh(z);
}

// ================== gemm_big: 256x256 tile, BK=64, 8-wave, 8-phase counted-vmcnt schedule ==================
// Dz2 = A1p(16384x1024) @ W12p(1024x2048), fused tanh-delta epilogue.
// grid (64, 8), 512 threads (8 waves: wm=wave>>2, wn=wave&3), per-wave 128x64 output (8x4 16x16 frags).
// LDS: As[2][32KB] + Bs[2][32KB] = 128 KiB (1 block/CU). Operands pre-packed in MFMA fragment order
// -> every ds_read_b128 is the contiguous lane*16B pattern (0 bank conflicts), staging is linear.
//
// v2: no explicit lgkmcnt / sched_barrier — the ds_reads are compiler-visible, so hipcc emits
// fine-grained lgkmcnt(N) and the first MFMA starts as soon as its own frags land (reads drain
// under the MFMA shadow). Correctness: each read's consumer MFMA is in the same phase (reads can't
// sink past a conflicting stage); the vmcnt-gate asm ("memory" clobber) blocks reads hoisting above
// the staging gates; raw s_barrier pairs bound wave skew exactly as before.
//
// Stage schedule (tile T computed ph1-4 in buf0, T+1 ph5-8 in buf1; per phase 1 half-tile staged):
//   ph1: T+1.A0   ph2: T+1.A1   ph3: T+2.B0   ph4: T+2.B1 + vmcnt(4)
//   ph5: T+2.A0   ph6: T+2.A1   ph7: T+3.B0   ph8: T+3.B1 + vmcnt(4)
// vmcnt(4) at ph4/ph8 leaves exactly the last 2 half-tile stages in flight -> next tile resident.
__device__ __forceinline__ void stage_half(const short* __restrict__ base, short* lbase,
                                           int wave, int lane){
    const short* s = base + (size_t)(wave * 2) * 512 + lane * 8;
    short* d = lbase + (wave * 2) * 512;
    gld_lds16(s, d);
    gld_lds16(s + 512, d + 512);
}

__global__ __launch_bounds__(512, 2) void gemm_big(
    const short* __restrict__ Ap, const short* __restrict__ Bp,
    const float* __restrict__ TB, const float* __restrict__ wrow,
    float* __restrict__ dacc){
    __shared__ __align__(16) short As[2][16384];
    __shared__ __align__(16) short Bs[2][16384];
    __shared__ float redn[256];
    int tid = threadIdx.x;
    int wave = tid >> 6, lane = tid & 63;
    int wm = wave >> 2, wn = wave & 3;
    int bm = blockIdx.x, bn = blockIdx.y;
    int quad = lane >> 4, llo = lane & 15;
    const short* Ab = Ap + (size_t)bm * 16 * 32 * 512;   // 256-row slab: 16 ktiles x 32 chunks x 1KB
    const short* Bb = Bp + (size_t)bn * 16 * 32 * 512;   // 256-col slab

    f32x4 acc[8][4];
    #pragma unroll
    for (int i = 0; i < 8; ++i)
        #pragma unroll
        for (int j = 0; j < 4; ++j) acc[i][j] = (f32x4){0.f, 0.f, 0.f, 0.f};

    bf16x8 af[4][2];   // current m-quad A frags [i][kk]
    bf16x8 bfr[4][2];  // all 4 n frags [nt_local][kk], held across the tile

#define BARX() __builtin_amdgcn_s_barrier()
#define GATE4() asm volatile("s_waitcnt vmcnt(4)" ::: "memory")
#define GATE0() asm volatile("s_waitcnt vmcnt(0)" ::: "memory")
#define STAGE_A(kt, h, buf) stage_half(Ab + ((size_t)(kt) * 32 + (h) * 16) * 512, &As[buf][(h) * 16 * 512], wave, lane)
#define STAGE_B(kt, h, buf) stage_half(Bb + ((size_t)(kt) * 32 + (h) * 16) * 512, &Bs[buf][(h) * 16 * 512], wave, lane)
#define RD_A(buf, ib) { _Pragma("unroll") for (int i_ = 0; i_ < 4; ++i_)                                   \
        _Pragma("unroll") for (int k_ = 0; k_ < 2; ++k_)                                                   \
            af[i_][k_] = *(const bf16x8*)&As[buf][(((wm * 8 + (ib) + i_) * 2 + k_) * 512) + lane * 8]; }
#define RD_B(buf, jb) { _Pragma("unroll") for (int j_ = 0; j_ < 2; ++j_)                                   \
        _Pragma("unroll") for (int k_ = 0; k_ < 2; ++k_)                                                   \
            bfr[(jb) + j_][k_] = *(const bf16x8*)&Bs[buf][(((wn * 4 + (jb) + j_) * 2 + k_) * 512) + lane * 8]; }
#define MFMA16(mb, nb) { _Pragma("unroll") for (int k_ = 0; k_ < 2; ++k_)                                  \
        _Pragma("unroll") for (int i_ = 0; i_ < 4; ++i_)                                                   \
        _Pragma("unroll") for (int j_ = 0; j_ < 2; ++j_)                                                   \
            acc[(mb) + i_][(nb) + j_] = __builtin_amdgcn_mfma_f32_16x16x32_bf16(                           \
                af[i_][k_], bfr[(nb) + j_][k_], acc[(mb) + i_][(nb) + j_], 0, 0, 0); }
#define PH(reads, stage, mfma, gate) do {                                                                  \
        reads; stage;                                                                                      \
        BARX();                                                                                            \
        __builtin_amdgcn_s_setprio(1); mfma; __builtin_amdgcn_s_setprio(0);                                \
        gate;                                                                                              \
        BARX(); } while (0)

    // prologue: tile0 (B then A) + tile1 B; vmcnt(4) -> tile0 fully resident, 1.B0/1.B1 in flight
    STAGE_B(0, 0, 0); STAGE_B(0, 1, 0);
    STAGE_A(0, 0, 0); STAGE_A(0, 1, 0);
    STAGE_B(1, 0, 1); STAGE_B(1, 1, 1);
    GATE4();
    BARX();

    for (int T = 0; T < 14; T += 2){
        PH(RD_A(0, 0); RD_B(0, 0), STAGE_A(T + 1, 0, 1), MFMA16(0, 0), );
        PH(RD_B(0, 2),             STAGE_A(T + 1, 1, 1), MFMA16(0, 2), );
        PH(RD_A(0, 4),             STAGE_B(T + 2, 0, 0), MFMA16(4, 0), );
        PH(                      , STAGE_B(T + 2, 1, 0), MFMA16(4, 2), GATE4());
        PH(RD_A(1, 0); RD_B(1, 0), STAGE_A(T + 2, 0, 0), MFMA16(0, 0), );
        PH(RD_B(1, 2),             STAGE_A(T + 2, 1, 0), MFMA16(0, 2), );
        PH(RD_A(1, 4),             STAGE_B(T + 3, 0, 1), MFMA16(4, 0), );
        PH(                      , STAGE_B(T + 3, 1, 1), MFMA16(4, 2), GATE4());
    }
    // peeled final iteration: T=14 (tiles 14,15); only 15.A0/A1 remain to stage
    PH(RD_A(0, 0); RD_B(0, 0), STAGE_A(15, 0, 1), MFMA16(0, 0), );
    PH(RD_B(0, 2),             STAGE_A(15, 1, 1), MFMA16(0, 2), );
    PH(RD_A(0, 4),           ,                    MFMA16(4, 0), );
    PH(                      , ,                  MFMA16(4, 2), GATE0());
    PH(RD_A(1, 0); RD_B(1, 0), ,                  MFMA16(0, 0), );
    PH(RD_B(1, 2),             ,                  MFMA16(0, 2), );
    PH(RD_A(1, 4),             ,                  MFMA16(4, 0), );
    PH(                      , ,                  MFMA16(4, 2), );

#undef PH
#undef MFMA16
#undef RD_B
#undef RD_A
#undef STAGE_B
#undef STAGE_A
#undef GATE0
#undef GATE4
#undef BARX

    // fused epilogue: tanh(zb+dz)-tanh(zb) = tdz*(1-tb^2)/(1+tb*tdz), weighted by wrow, reduce over m
    int nj[4];
    #pragma unroll
    for (int j = 0; j < 4; ++j) nj[j] = bn * 256 + wn * 64 + j * 16 + llo;
    float part[4] = {};
    #pragma unroll
    for (int i = 0; i < 8; ++i){
        #pragma unroll
        for (int r = 0; r < 4; ++r){
            int m = bm * 256 + wm * 128 + i * 16 + quad * 4 + r;
            float wr = wrow[m];
            const float* trow = TB + (size_t)(m & 255) * HBc;
            #pragma unroll
            for (int j = 0; j < 4; ++j){
                float tb  = trow[nj[j]];
                float tdz = fast_tanh(acc[i][j][r]);
                float num = tdz * (1.0f - tb * tb);
                float den = 1.0f + tb * tdz;
                part[j] += wr * num * __builtin_amdgcn_rcpf(den);
            }
        }
    }
    #pragma unroll
    for (int j = 0; j < 4; ++j){
        part[j] += __shfl_xor(part[j], 16);
        part[j] += __shfl_xor(part[j], 32);
    }
    if (tid < 256) redn[tid] = 0.f;
    __syncthreads();
    if (quad == 0){
        #pragma unroll
        for (int j = 0; j < 4; ++j)
            atomicAdd(&redn[wn * 64 + j * 16 + llo], part[j]);
    }
    __syncthreads();
    if (tid < 256) atomicAdd(&dacc[bn * 256 + tid], redn[tid]);
}

// ---------------- si = dacc @ Wb2, split over 8 blocks (out pre-zeroed in prep) ----------------
__global__ void out_kernel(const float* __restrict__ dacc, const float* __restrict__ Wb2,
                           float* __restrict__ out){
    __shared__ float red[4][64];
    int tid = threadIdx.x;
    int g = tid & 63, seg = tid >> 6;
    int h0 = blockIdx.x * 256 + seg * 64;
    float s = 0.f;
    #pragma unroll 8
    for (int hh = 0; hh < 64; ++hh)
        s += dacc[h0 + hh] * Wb2[(size_t)(h0 + hh) * GOUTc + g];
    red[seg][g] = s;
    __syncthreads();
    if (tid < 64)
        atomicAdd(&out[tid], red[0][tid] + red[1][tid] + red[2][tid] + red[3][tid]);
}

extern "C" void kernel_launch(void* const* d_in, const int* in_sizes, int n_in,
                              void* d_out, int out_size, void* d_ws, size_t ws_size,
                              hipStream_t stream){
    const float* X         = (const float*)d_in[0];
    const float* Y         = (const float*)d_in[1];
    const float* R         = (const float*)d_in[2];
    const float* stoich    = (const float*)d_in[3];
    const float* times_t   = (const float*)d_in[4];
    const float* times_tau = (const float*)d_in[5];
    const float* Wx1 = (const float*)d_in[6];
    const float* bx1 = (const float*)d_in[7];
    const float* Wx2 = (const float*)d_in[8];
    const float* bx2 = (const float*)d_in[9];
    const float* Wih = (const float*)d_in[10];
    const float* Whh = (const float*)d_in[11];
    const float* bh  = (const float*)d_in[12];
    const float* Wb1 = (const float*)d_in[13];
    const float* bb1 = (const float*)d_in[14];
    const float* Wb2 = (const float*)d_in[15];
    // d_in[16] = bb2: cancels in (nn_disp - nn), unused
    const int* kp  = (const int*)d_in[17];
    const int* kpp = (const int*)d_in[18];
    const int* qp  = (const int*)d_in[19];
    const int* qpp = (const int*)d_in[20];
    float* out = (float*)d_out;

    float* ws     = (float*)d_ws;
    float* hb0    = ws;                        // 512
    float* hb1    = ws + 512;                  // 512
    float* cY     = ws + 1024;                 // 2048
    float* dacc   = ws + 3072;                 // 2048
    float* wrow   = ws + 5120;                 // 64*256 = 16384
    float* SW     = ws + 21504;                // 64*1024 = 65536
    float* XW     = ws + 87040;                // 256*1024 = 262144
    float* T1     = ws + 349184;               // 256*1024 = 262144
    float* eXb    = ws + 611328;               // 256*512 = 131072
    float* TB     = ws + 742400;               // 256*2048 = 524288
    float* Z2Bacc = ws + 1266688;              // 256*2048 = 524288
    short* A1p    = (short*)(ws + 1790976);    // 16384*1024 bf16 = 8,388,608 float slots
    short* Wx2a   = (short*)(ws + 10179584);   // 1024*512 bf16 = 262,144 float slots
    short* Wb1p   = (short*)(ws + 10441728);   // 512*2048 bf16 = 524,288 float slots
    short* W12p   = (short*)(ws + 10966016);   // 1024*2048 bf16 = 1,048,576 float slots
    int*   cnt    = (int*)(ws + 12014592);     // 1 int (RNN step counter)
    // total ws use: ~12.0M floats = 48.1 MB

    prep_kernel      <<<4673, 256, 0, stream>>>(stoich, Wx1, Wx2, Wb1, X, R, bx1, bx2, kpp, qpp,
                                                SW, Wx2a, Wb1p, XW, T1, wrow, hb0, dacc, out,
                                                eXb, Z2Bacc, cnt);
    w12_act_ex_kernel<<<8840, 256, 0, stream>>>(Wx2a, Wb1p, W12p, XW, T1, SW, A1p, Wx2, eXb,
                                                Y, Wih, Whh, bh, Wb1, bb1, kp, qp, hb0, hb1, cnt, cY);
    z2acc_kernel     <<<512,  256, 0, stream>>>(eXb, Wb1, Z2Bacc);
    tb_kernel        <<<2048, 256, 0, stream>>>(Z2Bacc, Wb1, cY, times_t, times_tau, kp, TB);
    gemm_big         <<<dim3(64, 8), 512, 0, stream>>>(A1p, W12p, TB, wrow, dacc);
    out_kernel       <<<8,    256, 0, stream>>>(dacc, Wb2, out);
}

// Round 3
// 269.479 us; speedup vs baseline: 1.1485x; 1.1485x over previous
//
#include <hip/hip_runtime.h>
#include <math.h>

// Shapes (fixed by the reference)
#define DXc   16
#define MRc   64
#define MBARc 256
#define NTc   9
#define DYc   8
#define HXc   1024
#define EXc   512
#define HRc   512
#define HBc   2048
#define GOUTc 64
#define TOTc  2049   // (NT-1)*MBAR + 1

using bf16x8 = __attribute__((ext_vector_type(8))) short;
using f32x4  = __attribute__((ext_vector_type(4))) float;

typedef unsigned int u32;
typedef u32 __attribute__((address_space(1))) gbl_u32;
typedef u32 __attribute__((address_space(3))) lds_u32;

__device__ __forceinline__ float fast_tanh(float x){
    float e = __expf(2.0f * x);
    return 1.0f - 2.0f / (e + 1.0f);
}

// fp32 -> bf16 round-to-nearest-even (bit pattern in a short)
__device__ __forceinline__ short f2bf(float f){
    unsigned u = __builtin_bit_cast(unsigned, f);
    u = (u + 0x7FFFu + ((u >> 16) & 1u)) >> 16;
    return (short)u;
}

// async global->LDS: each lane loads 16 B from g + lane*16; LDS dest = base + lane*16
__device__ __forceinline__ void gld_lds16(const short* g, short* l){
    __builtin_amdgcn_global_load_lds((const gbl_u32*)g, (lds_u32*)l, 16, 0, 0);
}

// ---------------- prep: SW + packs (Wx2a A-layout, Wb1p B-layout) + XW/T1 + wrow + inits ----------------
// grid 4673 x 256
__global__ void prep_kernel(const float* __restrict__ stoich, const float* __restrict__ Wx1,
                            const float* __restrict__ Wx2, const float* __restrict__ Wb1,
                            const float* __restrict__ X, const float* __restrict__ R,
                            const float* __restrict__ bx1, const float* __restrict__ bx2,
                            const float* __restrict__ bb1,
                            const int* kpptr, const int* qpptr,
                            float* __restrict__ SW, short* __restrict__ Wx2a,
                            short* __restrict__ Wb1p, float* __restrict__ XW,
                            float* __restrict__ T1, float* __restrict__ wrow,
                            float* __restrict__ hb0, float* __restrict__ dacc,
                            float* __restrict__ outz, float* __restrict__ eXb,
                            float* __restrict__ Z2Bacc, float* __restrict__ cY,
                            int* __restrict__ cnt){
    int b = blockIdx.x, tid = threadIdx.x;
    if (b < 256){
        // SW[j][c] = stoich[:,j] @ Wx1
        int idx = b * 256 + tid;
        int j = idx >> 10, c = idx & 1023;
        float acc = 0.f;
        #pragma unroll
        for (int d = 0; d < DXc; ++d) acc += stoich[d * MRc + j] * Wx1[d * HXc + c];
        SW[idx] = acc;
    } else if (b < 512){
        // pack Wx2 (1024x512) into MFMA A-fragment order (M=c rows, K=e), KTOT=16
        size_t grp = (size_t)(b - 256) * 256 + tid;    // 65536 groups
        int lane = grp & 63;
        size_t t2 = grp >> 6;
        int kt = t2 & 15, mt = t2 >> 4;                // mt 0..63
        int c  = mt * 16 + (lane & 15);
        int e0 = kt * 32 + ((lane >> 4) << 3);
        short o8[8];
        #pragma unroll
        for (int jj = 0; jj < 8; ++jj) o8[jj] = f2bf(Wx2[(size_t)c * EXc + e0 + jj]);
        *(bf16x8*)(Wx2a + grp * 8) = *(bf16x8*)o8;
    } else if (b < 1024){
        // pack Wb1 rows 1..512 (512x2048) into B-fragment order, KTOT=16
        size_t grp = (size_t)(b - 512) * 256 + tid;
        int lane = grp & 63;
        size_t t2 = grp >> 6;
        int kt = t2 & 15, nt = t2 >> 4;
        int n  = nt * 16 + (lane & 15);
        int k0 = kt * 32 + ((lane >> 4) << 3);
        short o8[8];
        #pragma unroll
        for (int jj = 0; jj < 8; ++jj) o8[jj] = f2bf(Wb1[(size_t)(1 + k0 + jj) * HBc + n]);
        *(bf16x8*)(Wb1p + grp * 8) = *(bf16x8*)o8;
    } else if (b < 2048){
        // XW = Xbase@Wx1 + bx1 ; T1 = tanh(XW)
        int idx = (b - 1024) * 256 + tid;
        int m = idx >> 10, c = idx & 1023;
        int base = kpptr[0] * MBARc;
        const float* xr = X + ((size_t)qpptr[0] * TOTc + base + m) * DXc;
        float acc = bx1[c];
        #pragma unroll
        for (int d = 0; d < DXc; ++d) acc += xr[d] * Wx1[d * HXc + c];
        XW[idx] = acc;
        T1[idx] = fast_tanh(acc);
    } else if (b < 2112){
        // wrow[j*256+m] = valid(j,m) * R_delta
        int j = b - 2048, m = tid;
        int base = kpptr[0] * MBARc;
        int qp = qpptr[0];
        const float* xr = X + ((size_t)qp * TOTc + base + m) * DXc;
        bool valid = true;
        #pragma unroll
        for (int d = 0; d < DXc; ++d) valid = valid && (xr[d] + stoich[d * MRc + j] >= 0.f);
        size_t rb = (size_t)qp * TOTc * MRc;
        float rd = R[rb + (size_t)(base + 1 + m) * MRc + j] - R[rb + (size_t)(base + m) * MRc + j];
        wrow[j * MBARc + m] = valid ? rd : 0.f;
    } else if (b == 2112){
        hb0[tid] = 0.f; hb0[tid + 256] = 0.f;
        #pragma unroll
        for (int l = 0; l < 8; ++l) dacc[tid + l * 256] = 0.f;
        #pragma unroll
        for (int l = 0; l < 8; ++l) cY[tid + l * 256] = bb1[tid + l * 256];
        if (tid < GOUTc) outz[tid] = 0.f;
        if (tid == 0) cnt[0] = 0;
    } else if (b < 2625){
        // eXb init = bx2 (broadcast per row); 512 blocks, 131072 elems
        int idx = (b - 2113) * 256 + tid;
        eXb[idx] = bx2[idx & 511];
    } else {
        // Z2Bacc = 0; 2048 blocks, 524288 elems
        Z2Bacc[(size_t)(b - 2625) * 256 + tid] = 0.f;
    }
}

// ---------------- act_ex: act_delta + exbase (no big LDS -> high occupancy for act blocks) ----------------
// blocks [0,512):    exbase split-K -> eXb (+= T1 @ Wx2)
// blocks [512,8704): act_delta -> A1p
__global__ __launch_bounds__(256) void act_ex_kernel(
    const float* __restrict__ XW, const float* __restrict__ T1,
    const float* __restrict__ SW, short* __restrict__ A1p,
    const float* __restrict__ Wx2, float* __restrict__ eXb){
    int b = blockIdx.x, tid = threadIdx.x;
    if (b < 512){
        // ---- exbase split-K: eXb += T1 @ Wx2 (eXb pre-init to bx2) ----
        __shared__ float t1s[8 * 128];
        int bb = b;                          // 0..511
        int mg = bb & 31, eh = (bb >> 5) & 1, kq = bb >> 6;
        int m0 = mg * 8, e = eh * 256 + tid, k0 = kq * 128;
        #pragma unroll
        for (int l = 0; l < 4; ++l){
            int idx = tid + l * 256;
            t1s[idx] = T1[(size_t)(m0 + (idx >> 7)) * HXc + k0 + (idx & 127)];
        }
        __syncthreads();
        float acc[8] = {};
        #pragma unroll 4
        for (int kk = 0; kk < 128; ++kk){
            float wv = Wx2[(size_t)(k0 + kk) * EXc + e];
            #pragma unroll
            for (int mm = 0; mm < 8; ++mm) acc[mm] += t1s[mm * 128 + kk] * wv;
        }
        #pragma unroll
        for (int mm = 0; mm < 8; ++mm)
            atomicAdd(&eXb[(size_t)(m0 + mm) * EXc + e], acc[mm]);
    } else {
        // ---- act_delta: A1p = bf16(tanh(XW+SW[j]) - T1), packed for gemm_big staging ----
        // layout: t2 = j*512 + kt*32 + mt*2 + kk ; value at m=j*256+mt*16+(lane&15),
        //         k = kt*64 + kk*32 + (lane>>4)*8 + e
        size_t grp = (size_t)(b - 512) * 256 + tid;  // 2,097,152 groups
        int lane = (int)(grp & 63);
        size_t t2 = grp >> 6;
        int kk = (int)(t2 & 1);
        int mt = (int)((t2 >> 1) & 15);
        int kt = (int)((t2 >> 5) & 15);
        int j  = (int)(t2 >> 9);             // 0..63 (= 256-row slab = reaction index)
        int mloc = mt * 16 + (lane & 15);    // 0..255
        int c0 = kt * 64 + kk * 32 + ((lane >> 4) << 3);
        const float* xwr = XW + (size_t)mloc * HXc + c0;
        const float* t1r = T1 + (size_t)mloc * HXc + c0;
        const float* swr = SW + (size_t)j * HXc + c0;
        short o8[8];
        #pragma unroll
        for (int i = 0; i < 8; ++i)
            o8[i] = f2bf(fast_tanh(xwr[i] + swr[i]) - t1r[i]);
        *(bf16x8*)(A1p + grp * 8) = *(bf16x8*)o8;
    }
}

// ---------------- RNN: 8 blocks x 512 threads, Whh slice cached in LDS (latency-immune steps) ----------------
// Cross-block data passes ONLY through agent-scope atomic store/load; counter-gated per step.
__global__ __launch_bounds__(512) void rnn_kernel(
    const float* __restrict__ Y, const float* __restrict__ Wih,
    const float* __restrict__ Whh, const float* __restrict__ bh,
    const int* kptr, const int* qptr,
    float* __restrict__ hb0, float* __restrict__ hb1,
    int* __restrict__ cnt){
    __shared__ float whs[HRc * 64];   // 512 x 64 slice of Whh = 128 KB
    __shared__ float hs[HRc];
    __shared__ float psum[8][64];
    int tid = threadIdx.x;
    int o = tid & 63, seg = tid >> 6;
    int b = blockIdx.x;
    int out = b * 64 + o;
    int k = kptr[0], q = qptr[0];
    // preload Whh[:, b*64 : b*64+64] -> whs[k][o]  (coalesced: each wave reads one 256B row segment)
    #pragma unroll
    for (int l = 0; l < 64; ++l){
        int idx = l * 512 + tid;
        whs[idx] = Whh[(size_t)(idx >> 6) * HRc + b * 64 + (idx & 63)];
    }
    hs[tid] = 0.f;
    __syncthreads();
    for (int s = 0; s < 8; ++s){
        float* dst = (s & 1) ? hb0 : hb1;
        if (s > 0){
            const float* src = (s & 1) ? hb1 : hb0;
            if (tid == 0){
                int guard = 0;
                while (__hip_atomic_load(cnt, __ATOMIC_ACQUIRE, __HIP_MEMORY_SCOPE_AGENT) < 8 * s
                       && ++guard < (1 << 26)) {}
            }
            __syncthreads();
            hs[tid] = __hip_atomic_load(src + tid, __ATOMIC_RELAXED, __HIP_MEMORY_SCOPE_AGENT);
            __syncthreads();
        }
        int t = k + 1 + s;
        if (t < NTc){
            int k0 = seg * 64;
            float a0 = 0.f, a1 = 0.f, a2 = 0.f, a3 = 0.f;
            #pragma unroll
            for (int kk = 0; kk < 64; kk += 4){
                a0 += hs[k0 + kk + 0] * whs[(k0 + kk + 0) * 64 + o];
                a1 += hs[k0 + kk + 1] * whs[(k0 + kk + 1) * 64 + o];
                a2 += hs[k0 + kk + 2] * whs[(k0 + kk + 2) * 64 + o];
                a3 += hs[k0 + kk + 3] * whs[(k0 + kk + 3) * 64 + o];
            }
            psum[seg][o] = (a0 + a1) + (a2 + a3);
            __syncthreads();
            if (seg == 0){
                float a = 0.f;
                #pragma unroll
                for (int r = 0; r < 8; ++r) a += psum[r][o];
                const float* y = Y + (q * NTc + t) * DYc;
                float z = bh[out];
                #pragma unroll
                for (int d = 0; d < DYc; ++d) z += y[d] * Wih[d * HRc + out];
                __hip_atomic_store(dst + out, fast_tanh(z + a), __ATOMIC_RELEASE, __HIP_MEMORY_SCOPE_AGENT);
            }
            __syncthreads();
        } else {
            if (seg == 0)
                __hip_atomic_store(dst + out, hs[out], __ATOMIC_RELEASE, __HIP_MEMORY_SCOPE_AGENT);
            __syncthreads();
        }
        if (tid == 0)
            __hip_atomic_fetch_add(cnt, 1, __ATOMIC_RELEASE, __HIP_MEMORY_SCOPE_AGENT);
    }
}

// ---- MFMA helpers (4x4 grid, used by w12) ----
#define MMGRID(aa, bb) {                                                       \
    _Pragma("unroll") for (int i_ = 0; i_ < 4; ++i_)                           \
        _Pragma("unroll") for (int j_ = 0; j_ < 4; ++j_)                       \
            acc[i_][j_] = __builtin_amdgcn_mfma_f32_16x16x32_bf16(aa[i_], bb[j_], acc[i_][j_], 0, 0, 0); }

// stage BK=32 (1 kt): 8 A-chunks + 8 B-chunks of 1 KB; wave w stages 4 chunks
__device__ __forceinline__ void stage32(const short* __restrict__ Ap, const short* __restrict__ Bp,
                                        short* As, short* Bs,
                                        int at0, int bt0, int s, int KTOT, int wave, int lane){
    #pragma unroll
    for (int c = 0; c < 4; ++c){
        int ci = wave * 4 + c;            // 0..15
        int half = ci >> 3;               // 0 = A, 1 = B
        int t    = ci & 7;
        const short* src = half ? (Bp + ((size_t)(bt0 + t) * KTOT + s) * 512 + lane * 8)
                                : (Ap + ((size_t)(at0 + t) * KTOT + s) * 512 + lane * 8);
        short* dst = (half ? Bs : As) + t * 512;
        gld_lds16(src, dst);
    }
}

// compute one stage (1 kt x 16 MFMA per wave) from LDS
#define STAGE_COMPUTE(As, Bs) {                                                       \
    bf16x8 af[4], bfr[4];                                                             \
    _Pragma("unroll") for (int i_ = 0; i_ < 4; ++i_)                                  \
        af[i_] = *(const bf16x8*)((As) + ((wm * 4 + i_) * 512) + lane * 8);           \
    _Pragma("unroll") for (int j_ = 0; j_ < 4; ++j_)                                  \
        bfr[j_] = *(const bf16x8*)((Bs) + ((wn * 4 + j_) * 512) + lane * 8);          \
    MMGRID(af, bfr); }

// ---------------- z2acc + w12 + cY (one dispatch; w12/cY latency hidden under z2acc) ----------------
// blocks [0,128):   w12 = Wx2bf @ Wb1midbf -> W12p (B-layout for gemm_big)
// blocks [128,160): cY += eY-chunk @ Wb1[513:1025]  (cY pre-init to bb1 in prep)
// blocks [160,672): z2acc split-K: Z2Bacc += eXb @ Wb1[1:513]
__global__ __launch_bounds__(256) void z2w12cy_kernel(
    const float* __restrict__ eXb, const float* __restrict__ Wb1,
    float* __restrict__ Z2Bacc,
    const short* __restrict__ Wx2a, const short* __restrict__ Wb1p,
    short* __restrict__ W12p,
    const float* __restrict__ hb0, float* __restrict__ cY){
    __shared__ __align__(16) short Asb[2][4096];
    __shared__ __align__(16) short Bsb[2][4096];
    int b = blockIdx.x, tid = threadIdx.x;
    if (b < 128){
        // ---- w12: 128x128 tiles, K=512 (S=16) ----
        const int KTOT = 16, S = 16;
        int bw = b;
        int wave = tid >> 6, lane = tid & 63;
        int wm = wave >> 1, wn = wave & 1;
        int bx = bw & 15, by = bw >> 4;
        int quad = lane >> 4, llo = lane & 15;
        f32x4 acc[4][4];
        #pragma unroll
        for (int i = 0; i < 4; ++i)
            #pragma unroll
            for (int j = 0; j < 4; ++j) acc[i][j] = (f32x4){0.f, 0.f, 0.f, 0.f};
        stage32(Wx2a, Wb1p, Asb[0], Bsb[0], by * 8, bx * 8, 0, KTOT, wave, lane);
        for (int s = 0; s < S; ++s){
            int buf = s & 1;
            __syncthreads();
            if (s + 1 < S)
                stage32(Wx2a, Wb1p, Asb[buf ^ 1], Bsb[buf ^ 1], by * 8, bx * 8, s + 1, KTOT, wave, lane);
            STAGE_COMPUTE(Asb[buf], Bsb[buf]);
        }
        // write W12[c][h] into gemm_big's B layout: chunk = [h>>8][c>>6][((h>>4)&15)*2 + ((c>>5)&1)],
        // lane = ((c>>3)&3)*16 + (h&15), elem = c&7
        #pragma unroll
        for (int j = 0; j < 4; ++j){
            int h = bx * 128 + wn * 64 + j * 16 + llo;
            #pragma unroll
            for (int i = 0; i < 4; ++i){
                #pragma unroll
                for (int r = 0; r < 4; ++r){
                    int c = by * 128 + wm * 64 + i * 16 + quad * 4 + r;
                    size_t idx = ((((size_t)(h >> 8) * 16 + (c >> 6)) * 32)
                                  + ((h >> 4) & 15) * 2 + ((c >> 5) & 1)) * 512
                               + (size_t)(((c >> 3) & 3) * 16 + (h & 15)) * 8 + (c & 7);
                    W12p[idx] = f2bf(acc[i][j][r]);
                }
            }
        }
    } else if (b < 160){
        // ---- cY partial: 32 blocks = 4 e-chunks x 8 h-chunks ----
        __shared__ float hs2[128];
        int bb = b - 128;
        int e0 = (bb >> 3) * 128, h = (bb & 7) * 256 + tid;
        if (tid < 128) hs2[tid] = hb0[e0 + tid];
        __syncthreads();
        float acc = 0.f;
        #pragma unroll 4
        for (int e = 0; e < 128; ++e)
            acc += hs2[e] * Wb1[(size_t)(1 + EXc + e0 + e) * HBc + h];
        atomicAdd(&cY[h], acc);
    } else {
        // ---- z2acc split-K ----
        __shared__ float exs[8 * 256];
        int bz = b - 160;
        int mg = bz & 31, hh = (bz >> 5) & 7, kq = bz >> 8;
        int m0 = mg * 8, h = hh * 256 + tid, k0 = kq * 256;
        #pragma unroll
        for (int l = 0; l < 8; ++l){
            int idx = tid + l * 256;
            exs[idx] = eXb[(size_t)(m0 + (idx >> 8)) * EXc + k0 + (idx & 255)];
        }
        __syncthreads();
        float acc[8] = {};
        #pragma unroll 4
        for (int kk = 0; kk < 256; ++kk){
            float wv = Wb1[(size_t)(1 + k0 + kk) * HBc + h];
            #pragma unroll
            for (int mm = 0; mm < 8; ++mm) acc[mm] += exs[mm * 256 + kk] * wv;
        }
        #pragma unroll
        for (int mm = 0; mm < 8; ++mm)
            atomicAdd(&Z2Bacc[(size_t)(m0 + mm) * HBc + h], acc[mm]);
    }
}

// ---------------- tb: TB = tanh(Z2Bacc + (tk+tau_m)*Wb1[0] + cY) ----------------
__global__ void tb_kernel(const float* __restrict__ Z2Bacc, const float* __restrict__ Wb1,
                          const float* __restrict__ cY, const float* __restrict__ times_t,
                          const float* __restrict__ times_tau, const int* kptr,
                          float* __restrict__ TB){
    int b = blockIdx.x, tid = threadIdx.x;
    int m = b >> 3, h = (b & 7) * 256 + tid;
    float tk = times_t[kptr[0]];
    size_t idx = (size_t)m * HBc + h;
    float z = Z2Bacc[idx] + (tk + times_tau[m]) * Wb1[h] + cY[h];
    TB[idx] = fast_tanh(z);
}

// ================== gemm_big: 256x256 tile, BK=64, 8-wave, 8-phase counted-vmcnt schedule ==================
// Dz2 = A1p(16384x1024) @ W12p(1024x2048), fused tanh-delta epilogue.
// grid (64, 8), 512 threads (8 waves: wm=wave>>2, wn=wave&3), per-wave 128x64 output (8x4 16x16 frags).
// LDS: As[2][32KB] + Bs[2][32KB] = 128 KiB (1 block/CU). Operands pre-packed in MFMA fragment order
// -> every ds_read_b128 is the contiguous lane*16B pattern (0 bank conflicts), staging is linear.
//
// No explicit lgkmcnt / sched_barrier — the ds_reads are compiler-visible, so hipcc emits
// fine-grained lgkmcnt(N) and the first MFMA starts as soon as its own frags land (reads drain
// under the MFMA shadow). The vmcnt-gate asm ("memory" clobber) blocks reads hoisting above
// the staging gates; raw s_barrier pairs bound wave skew.
//
// Stage schedule (tile T computed ph1-4 in buf0, T+1 ph5-8 in buf1; per phase 1 half-tile staged):
//   ph1: T+1.A0   ph2: T+1.A1   ph3: T+2.B0   ph4: T+2.B1 + vmcnt(4)
//   ph5: T+2.A0   ph6: T+2.A1   ph7: T+3.B0   ph8: T+3.B1 + vmcnt(4)
// vmcnt(4) at ph4/ph8 leaves exactly the last 2 half-tile stages in flight -> next tile resident.
__device__ __forceinline__ void stage_half(const short* __restrict__ base, short* lbase,
                                           int wave, int lane){
    const short* s = base + (size_t)(wave * 2) * 512 + lane * 8;
    short* d = lbase + (wave * 2) * 512;
    gld_lds16(s, d);
    gld_lds16(s + 512, d + 512);
}

__global__ __launch_bounds__(512, 2) void gemm_big(
    const short* __restrict__ Ap, const short* __restrict__ Bp,
    const float* __restrict__ TB, const float* __restrict__ wrow,
    float* __restrict__ dacc){
    __shared__ __align__(16) short As[2][16384];
    __shared__ __align__(16) short Bs[2][16384];
    __shared__ float redn[256];
    int tid = threadIdx.x;
    int wave = tid >> 6, lane = tid & 63;
    int wm = wave >> 2, wn = wave & 3;
    int bm = blockIdx.x, bn = blockIdx.y;
    int quad = lane >> 4, llo = lane & 15;
    const short* Ab = Ap + (size_t)bm * 16 * 32 * 512;   // 256-row slab: 16 ktiles x 32 chunks x 1KB
    const short* Bb = Bp + (size_t)bn * 16 * 32 * 512;   // 256-col slab

    f32x4 acc[8][4];
    #pragma unroll
    for (int i = 0; i < 8; ++i)
        #pragma unroll
        for (int j = 0; j < 4; ++j) acc[i][j] = (f32x4){0.f, 0.f, 0.f, 0.f};

    bf16x8 af[4][2];   // current m-quad A frags [i][kk]
    bf16x8 bfr[4][2];  // all 4 n frags [nt_local][kk], held across the tile

#define BARX() __builtin_amdgcn_s_barrier()
#define GATE4() asm volatile("s_waitcnt vmcnt(4)" ::: "memory")
#define GATE0() asm volatile("s_waitcnt vmcnt(0)" ::: "memory")
#define STAGE_A(kt, h, buf) stage_half(Ab + ((size_t)(kt) * 32 + (h) * 16) * 512, &As[buf][(h) * 16 * 512], wave, lane)
#define STAGE_B(kt, h, buf) stage_half(Bb + ((size_t)(kt) * 32 + (h) * 16) * 512, &Bs[buf][(h) * 16 * 512], wave, lane)
#define RD_A(buf, ib) { _Pragma("unroll") for (int i_ = 0; i_ < 4; ++i_)                                   \
        _Pragma("unroll") for (int k_ = 0; k_ < 2; ++k_)                                                   \
            af[i_][k_] = *(const bf16x8*)&As[buf][(((wm * 8 + (ib) + i_) * 2 + k_) * 512) + lane * 8]; }
#define RD_B(buf, jb) { _Pragma("unroll") for (int j_ = 0; j_ < 2; ++j_)                                   \
        _Pragma("unroll") for (int k_ = 0; k_ < 2; ++k_)                                                   \
            bfr[(jb) + j_][k_] = *(const bf16x8*)&Bs[buf][(((wn * 4 + (jb) + j_) * 2 + k_) * 512) + lane * 8]; }
#define MFMA16(mb, nb) { _Pragma("unroll") for (int k_ = 0; k_ < 2; ++k_)                                  \
        _Pragma("unroll") for (int i_ = 0; i_ < 4; ++i_)                                                   \
        _Pragma("unroll") for (int j_ = 0; j_ < 2; ++j_)                                                   \
            acc[(mb) + i_][(nb) + j_] = __builtin_amdgcn_mfma_f32_16x16x32_bf16(                           \
                af[i_][k_], bfr[(nb) + j_][k_], acc[(mb) + i_][(nb) + j_], 0, 0, 0); }
#define PH(reads, stage, mfma, gate) do {                                                                  \
        reads; stage;                                                                                      \
        BARX();                                                                                            \
        __builtin_amdgcn_s_setprio(1); mfma; __builtin_amdgcn_s_setprio(0);                                \
        gate;                                                                                              \
        BARX(); } while (0)

    // prologue: tile0 (B then A) + tile1 B; vmcnt(4) -> tile0 fully resident, 1.B0/1.B1 in flight
    STAGE_B(0, 0, 0); STAGE_B(0, 1, 0);
    STAGE_A(0, 0, 0); STAGE_A(0, 1, 0);
    STAGE_B(1, 0, 1); STAGE_B(1, 1, 1);
    GATE4();
    BARX();

    for (int T = 0; T < 14; T += 2){
        PH(RD_A(0, 0); RD_B(0, 0), STAGE_A(T + 1, 0, 1), MFMA16(0, 0), );
        PH(RD_B(0, 2),             STAGE_A(T + 1, 1, 1), MFMA16(0, 2), );
        PH(RD_A(0, 4),             STAGE_B(T + 2, 0, 0), MFMA16(4, 0), );
        PH(                      , STAGE_B(T + 2, 1, 0), MFMA16(4, 2), GATE4());
        PH(RD_A(1, 0); RD_B(1, 0), STAGE_A(T + 2, 0, 0), MFMA16(0, 0), );
        PH(RD_B(1, 2),             STAGE_A(T + 2, 1, 0), MFMA16(0, 2), );
        PH(RD_A(1, 4),             STAGE_B(T + 3, 0, 1), MFMA16(4, 0), );
        PH(                      , STAGE_B(T + 3, 1, 1), MFMA16(4, 2), GATE4());
    }
    // peeled final iteration: T=14 (tiles 14,15); only 15.A0/A1 remain to stage
    PH(RD_A(0, 0); RD_B(0, 0), STAGE_A(15, 0, 1), MFMA16(0, 0), );
    PH(RD_B(0, 2),             STAGE_A(15, 1, 1), MFMA16(0, 2), );
    PH(RD_A(0, 4),           ,                    MFMA16(4, 0), );
    PH(                      , ,                  MFMA16(4, 2), GATE0());
    PH(RD_A(1, 0); RD_B(1, 0), ,                  MFMA16(0, 0), );
    PH(RD_B(1, 2),             ,                  MFMA16(0, 2), );
    PH(RD_A(1, 4),             ,                  MFMA16(4, 0), );
    PH(                      , ,                  MFMA16(4, 2), );

#undef PH
#undef MFMA16
#undef RD_B
#undef RD_A
#undef STAGE_B
#undef STAGE_A
#undef GATE0
#undef GATE4
#undef BARX

    // fused epilogue: tanh(zb+dz)-tanh(zb) = tdz*(1-tb^2)/(1+tb*tdz), weighted by wrow, reduce over m
    int nj[4];
    #pragma unroll
    for (int j = 0; j < 4; ++j) nj[j] = bn * 256 + wn * 64 + j * 16 + llo;
    float part[4] = {};
    #pragma unroll
    for (int i = 0; i < 8; ++i){
        #pragma unroll
        for (int r = 0; r < 4; ++r){
            int m = bm * 256 + wm * 128 + i * 16 + quad * 4 + r;
            float wr = wrow[m];
            const float* trow = TB + (size_t)(m & 255) * HBc;
            #pragma unroll
            for (int j = 0; j < 4; ++j){
                float tb  = trow[nj[j]];
                float tdz = fast_tanh(acc[i][j][r]);
                float num = tdz * (1.0f - tb * tb);
                float den = 1.0f + tb * tdz;
                part[j] += wr * num * __builtin_amdgcn_rcpf(den);
            }
        }
    }
    #pragma unroll
    for (int j = 0; j < 4; ++j){
        part[j] += __shfl_xor(part[j], 16);
        part[j] += __shfl_xor(part[j], 32);
    }
    if (tid < 256) redn[tid] = 0.f;
    __syncthreads();
    if (quad == 0){
        #pragma unroll
        for (int j = 0; j < 4; ++j)
            atomicAdd(&redn[wn * 64 + j * 16 + llo], part[j]);
    }
    __syncthreads();
    if (tid < 256) atomicAdd(&dacc[bn * 256 + tid], redn[tid]);
}

// ---------------- si = dacc @ Wb2, split over 8 blocks (out pre-zeroed in prep) ----------------
__global__ void out_kernel(const float* __restrict__ dacc, const float* __restrict__ Wb2,
                           float* __restrict__ out){
    __shared__ float red[4][64];
    int tid = threadIdx.x;
    int g = tid & 63, seg = tid >> 6;
    int h0 = blockIdx.x * 256 + seg * 64;
    float s = 0.f;
    #pragma unroll 8
    for (int hh = 0; hh < 64; ++hh)
        s += dacc[h0 + hh] * Wb2[(size_t)(h0 + hh) * GOUTc + g];
    red[seg][g] = s;
    __syncthreads();
    if (tid < 64)
        atomicAdd(&out[tid], red[0][tid] + red[1][tid] + red[2][tid] + red[3][tid]);
}

extern "C" void kernel_launch(void* const* d_in, const int* in_sizes, int n_in,
                              void* d_out, int out_size, void* d_ws, size_t ws_size,
                              hipStream_t stream){
    const float* X         = (const float*)d_in[0];
    const float* Y         = (const float*)d_in[1];
    const float* R         = (const float*)d_in[2];
    const float* stoich    = (const float*)d_in[3];
    const float* times_t   = (const float*)d_in[4];
    const float* times_tau = (const float*)d_in[5];
    const float* Wx1 = (const float*)d_in[6];
    const float* bx1 = (const float*)d_in[7];
    const float* Wx2 = (const float*)d_in[8];
    const float* bx2 = (const float*)d_in[9];
    const float* Wih = (const float*)d_in[10];
    const float* Whh = (const float*)d_in[11];
    const float* bh  = (const float*)d_in[12];
    const float* Wb1 = (const float*)d_in[13];
    const float* bb1 = (const float*)d_in[14];
    const float* Wb2 = (const float*)d_in[15];
    // d_in[16] = bb2: cancels in (nn_disp - nn), unused
    const int* kp  = (const int*)d_in[17];
    const int* kpp = (const int*)d_in[18];
    const int* qp  = (const int*)d_in[19];
    const int* qpp = (const int*)d_in[20];
    float* out = (float*)d_out;

    float* ws     = (float*)d_ws;
    float* hb0    = ws;                        // 512
    float* hb1    = ws + 512;                  // 512
    float* cY     = ws + 1024;                 // 2048
    float* dacc   = ws + 3072;                 // 2048
    float* wrow   = ws + 5120;                 // 64*256 = 16384
    float* SW     = ws + 21504;                // 64*1024 = 65536
    float* XW     = ws + 87040;                // 256*1024 = 262144
    float* T1     = ws + 349184;               // 256*1024 = 262144
    float* eXb    = ws + 611328;               // 256*512 = 131072
    float* TB     = ws + 742400;               // 256*2048 = 524288
    float* Z2Bacc = ws + 1266688;              // 256*2048 = 524288
    short* A1p    = (short*)(ws + 1790976);    // 16384*1024 bf16 = 8,388,608 float slots
    short* Wx2a   = (short*)(ws + 10179584);   // 1024*512 bf16 = 262,144 float slots
    short* Wb1p   = (short*)(ws + 10441728);   // 512*2048 bf16 = 524,288 float slots
    short* W12p   = (short*)(ws + 10966016);   // 1024*2048 bf16 = 1,048,576 float slots
    int*   cnt    = (int*)(ws + 12014592);     // 1 int (RNN step counter)
    // total ws use: ~12.0M floats = 48.1 MB

    prep_kernel   <<<4673, 256, 0, stream>>>(stoich, Wx1, Wx2, Wb1, X, R, bx1, bx2, bb1, kpp, qpp,
                                             SW, Wx2a, Wb1p, XW, T1, wrow, hb0, dacc, out,
                                             eXb, Z2Bacc, cY, cnt);
    act_ex_kernel <<<8704, 256, 0, stream>>>(XW, T1, SW, A1p, Wx2, eXb);
    rnn_kernel    <<<8,    512, 0, stream>>>(Y, Wih, Whh, bh, kp, qp, hb0, hb1, cnt);
    z2w12cy_kernel<<<672,  256, 0, stream>>>(eXb, Wb1, Z2Bacc, Wx2a, Wb1p, W12p, hb0, cY);
    tb_kernel     <<<2048, 256, 0, stream>>>(Z2Bacc, Wb1, cY, times_t, times_tau, kp, TB);
    gemm_big      <<<dim3(64, 8), 512, 0, stream>>>(A1p, W12p, TB, wrow, dacc);
    out_kernel    <<<8,    256, 0, stream>>>(dacc, Wb2, out);
}

// Round 4
// 268.243 us; speedup vs baseline: 1.1538x; 1.0046x over previous
//
#include <hip/hip_runtime.h>
#include <math.h>

// Shapes (fixed by the reference)
#define DXc   16
#define MRc   64
#define MBARc 256
#define NTc   9
#define DYc   8
#define HXc   1024
#define EXc   512
#define HRc   512
#define HBc   2048
#define GOUTc 64
#define TOTc  2049   // (NT-1)*MBAR + 1

using bf16x8 = __attribute__((ext_vector_type(8))) short;
using f32x4  = __attribute__((ext_vector_type(4))) float;

typedef unsigned int u32;
typedef u32 __attribute__((address_space(1))) gbl_u32;
typedef u32 __attribute__((address_space(3))) lds_u32;

__device__ __forceinline__ float fast_tanh(float x){
    float e = __expf(2.0f * x);
    return 1.0f - 2.0f / (e + 1.0f);
}

// fp32 -> bf16 round-to-nearest-even (bit pattern in a short)
__device__ __forceinline__ short f2bf(float f){
    unsigned u = __builtin_bit_cast(unsigned, f);
    u = (u + 0x7FFFu + ((u >> 16) & 1u)) >> 16;
    return (short)u;
}

// async global->LDS: each lane loads 16 B from g + lane*16; LDS dest = base + lane*16
__device__ __forceinline__ void gld_lds16(const short* g, short* l){
    __builtin_amdgcn_global_load_lds((const gbl_u32*)g, (lds_u32*)l, 16, 0, 0);
}

// ---------------- prep: SW + packs (Wx2a A-layout, Wb1p B-layout) + XW/T1 + wrow + inits ----------------
// grid 4673 x 256
__global__ void prep_kernel(const float* __restrict__ stoich, const float* __restrict__ Wx1,
                            const float* __restrict__ Wx2, const float* __restrict__ Wb1,
                            const float* __restrict__ X, const float* __restrict__ R,
                            const float* __restrict__ bx1, const float* __restrict__ bx2,
                            const float* __restrict__ bb1,
                            const int* kpptr, const int* qpptr,
                            float* __restrict__ SW, short* __restrict__ Wx2a,
                            short* __restrict__ Wb1p, float* __restrict__ XW,
                            float* __restrict__ T1, float* __restrict__ wrow,
                            float* __restrict__ hb0, float* __restrict__ dacc,
                            float* __restrict__ outz, float* __restrict__ eXb,
                            float* __restrict__ Z2Bacc, float* __restrict__ cY,
                            int* __restrict__ cnt){
    int b = blockIdx.x, tid = threadIdx.x;
    if (b < 256){
        // SW[j][c] = stoich[:,j] @ Wx1
        int idx = b * 256 + tid;
        int j = idx >> 10, c = idx & 1023;
        float acc = 0.f;
        #pragma unroll
        for (int d = 0; d < DXc; ++d) acc += stoich[d * MRc + j] * Wx1[d * HXc + c];
        SW[idx] = acc;
    } else if (b < 512){
        // pack Wx2 (1024x512) into MFMA A-fragment order (M=c rows, K=e), KTOT=16
        size_t grp = (size_t)(b - 256) * 256 + tid;    // 65536 groups
        int lane = grp & 63;
        size_t t2 = grp >> 6;
        int kt = t2 & 15, mt = t2 >> 4;                // mt 0..63
        int c  = mt * 16 + (lane & 15);
        int e0 = kt * 32 + ((lane >> 4) << 3);
        short o8[8];
        #pragma unroll
        for (int jj = 0; jj < 8; ++jj) o8[jj] = f2bf(Wx2[(size_t)c * EXc + e0 + jj]);
        *(bf16x8*)(Wx2a + grp * 8) = *(bf16x8*)o8;
    } else if (b < 1024){
        // pack Wb1 rows 1..512 (512x2048) into B-fragment order, KTOT=16
        size_t grp = (size_t)(b - 512) * 256 + tid;
        int lane = grp & 63;
        size_t t2 = grp >> 6;
        int kt = t2 & 15, nt = t2 >> 4;
        int n  = nt * 16 + (lane & 15);
        int k0 = kt * 32 + ((lane >> 4) << 3);
        short o8[8];
        #pragma unroll
        for (int jj = 0; jj < 8; ++jj) o8[jj] = f2bf(Wb1[(size_t)(1 + k0 + jj) * HBc + n]);
        *(bf16x8*)(Wb1p + grp * 8) = *(bf16x8*)o8;
    } else if (b < 2048){
        // XW = Xbase@Wx1 + bx1 ; T1 = tanh(XW)
        int idx = (b - 1024) * 256 + tid;
        int m = idx >> 10, c = idx & 1023;
        int base = kpptr[0] * MBARc;
        const float* xr = X + ((size_t)qpptr[0] * TOTc + base + m) * DXc;
        float acc = bx1[c];
        #pragma unroll
        for (int d = 0; d < DXc; ++d) acc += xr[d] * Wx1[d * HXc + c];
        XW[idx] = acc;
        T1[idx] = fast_tanh(acc);
    } else if (b < 2112){
        // wrow[j*256+m] = valid(j,m) * R_delta
        int j = b - 2048, m = tid;
        int base = kpptr[0] * MBARc;
        int qp = qpptr[0];
        const float* xr = X + ((size_t)qp * TOTc + base + m) * DXc;
        bool valid = true;
        #pragma unroll
        for (int d = 0; d < DXc; ++d) valid = valid && (xr[d] + stoich[d * MRc + j] >= 0.f);
        size_t rb = (size_t)qp * TOTc * MRc;
        float rd = R[rb + (size_t)(base + 1 + m) * MRc + j] - R[rb + (size_t)(base + m) * MRc + j];
        wrow[j * MBARc + m] = valid ? rd : 0.f;
    } else if (b == 2112){
        hb0[tid] = 0.f; hb0[tid + 256] = 0.f;
        #pragma unroll
        for (int l = 0; l < 8; ++l) dacc[tid + l * 256] = 0.f;
        #pragma unroll
        for (int l = 0; l < 8; ++l) cY[tid + l * 256] = bb1[tid + l * 256];
        if (tid < GOUTc) outz[tid] = 0.f;
        if (tid == 0) cnt[0] = 0;
    } else if (b < 2625){
        // eXb init = bx2 (broadcast per row); 512 blocks, 131072 elems
        int idx = (b - 2113) * 256 + tid;
        eXb[idx] = bx2[idx & 511];
    } else {
        // Z2Bacc = 0; 2048 blocks, 524288 elems
        Z2Bacc[(size_t)(b - 2625) * 256 + tid] = 0.f;
    }
}

// ---------------- act_ex: act_delta + exbase (no big LDS -> high occupancy for act blocks) ----------------
// blocks [0,512):    exbase split-K -> eXb (+= T1 @ Wx2)
// blocks [512,8704): act_delta -> A1p
__global__ __launch_bounds__(256) void act_ex_kernel(
    const float* __restrict__ XW, const float* __restrict__ T1,
    const float* __restrict__ SW, short* __restrict__ A1p,
    const float* __restrict__ Wx2, float* __restrict__ eXb){
    int b = blockIdx.x, tid = threadIdx.x;
    if (b < 512){
        // ---- exbase split-K: eXb += T1 @ Wx2 (eXb pre-init to bx2) ----
        __shared__ float t1s[8 * 128];
        int bb = b;                          // 0..511
        int mg = bb & 31, eh = (bb >> 5) & 1, kq = bb >> 6;
        int m0 = mg * 8, e = eh * 256 + tid, k0 = kq * 128;
        #pragma unroll
        for (int l = 0; l < 4; ++l){
            int idx = tid + l * 256;
            t1s[idx] = T1[(size_t)(m0 + (idx >> 7)) * HXc + k0 + (idx & 127)];
        }
        __syncthreads();
        float acc[8] = {};
        #pragma unroll 4
        for (int kk = 0; kk < 128; ++kk){
            float wv = Wx2[(size_t)(k0 + kk) * EXc + e];
            #pragma unroll
            for (int mm = 0; mm < 8; ++mm) acc[mm] += t1s[mm * 128 + kk] * wv;
        }
        #pragma unroll
        for (int mm = 0; mm < 8; ++mm)
            atomicAdd(&eXb[(size_t)(m0 + mm) * EXc + e], acc[mm]);
    } else {
        // ---- act_delta: A1p = bf16(tanh(XW+SW[j]) - T1), packed for gemm_big staging ----
        // layout: t2 = j*512 + kt*32 + mt*2 + kk ; value at m=j*256+mt*16+(lane&15),
        //         k = kt*64 + kk*32 + (lane>>4)*8 + e
        size_t grp = (size_t)(b - 512) * 256 + tid;  // 2,097,152 groups
        int lane = (int)(grp & 63);
        size_t t2 = grp >> 6;
        int kk = (int)(t2 & 1);
        int mt = (int)((t2 >> 1) & 15);
        int kt = (int)((t2 >> 5) & 15);
        int j  = (int)(t2 >> 9);             // 0..63 (= 256-row slab = reaction index)
        int mloc = mt * 16 + (lane & 15);    // 0..255
        int c0 = kt * 64 + kk * 32 + ((lane >> 4) << 3);
        const float* xwr = XW + (size_t)mloc * HXc + c0;
        const float* t1r = T1 + (size_t)mloc * HXc + c0;
        const float* swr = SW + (size_t)j * HXc + c0;
        short o8[8];
        #pragma unroll
        for (int i = 0; i < 8; ++i)
            o8[i] = f2bf(fast_tanh(xwr[i] + swr[i]) - t1r[i]);
        *(bf16x8*)(A1p + grp * 8) = *(bf16x8*)o8;
    }
}

// ---------------- RNN: 8 blocks x 512 threads, Whh slice cached in LDS (latency-immune steps) ----------------
// Cross-block data passes ONLY through agent-scope atomic store/load; counter-gated per step.
__global__ __launch_bounds__(512) void rnn_kernel(
    const float* __restrict__ Y, const float* __restrict__ Wih,
    const float* __restrict__ Whh, const float* __restrict__ bh,
    const int* kptr, const int* qptr,
    float* __restrict__ hb0, float* __restrict__ hb1,
    int* __restrict__ cnt){
    __shared__ float whs[HRc * 64];   // 512 x 64 slice of Whh = 128 KB
    __shared__ float hs[HRc];
    __shared__ float psum[8][64];
    int tid = threadIdx.x;
    int o = tid & 63, seg = tid >> 6;
    int b = blockIdx.x;
    int out = b * 64 + o;
    int k = kptr[0], q = qptr[0];
    // preload Whh[:, b*64 : b*64+64] -> whs[k][o]  (coalesced: each wave reads one 256B row segment)
    #pragma unroll
    for (int l = 0; l < 64; ++l){
        int idx = l * 512 + tid;
        whs[idx] = Whh[(size_t)(idx >> 6) * HRc + b * 64 + (idx & 63)];
    }
    hs[tid] = 0.f;
    __syncthreads();
    for (int s = 0; s < 8; ++s){
        float* dst = (s & 1) ? hb0 : hb1;
        if (s > 0){
            const float* src = (s & 1) ? hb1 : hb0;
            if (tid == 0){
                int guard = 0;
                while (__hip_atomic_load(cnt, __ATOMIC_ACQUIRE, __HIP_MEMORY_SCOPE_AGENT) < 8 * s
                       && ++guard < (1 << 26)) {}
            }
            __syncthreads();
            hs[tid] = __hip_atomic_load(src + tid, __ATOMIC_RELAXED, __HIP_MEMORY_SCOPE_AGENT);
            __syncthreads();
        }
        int t = k + 1 + s;
        if (t < NTc){
            int k0 = seg * 64;
            float a0 = 0.f, a1 = 0.f, a2 = 0.f, a3 = 0.f;
            #pragma unroll
            for (int kk = 0; kk < 64; kk += 4){
                a0 += hs[k0 + kk + 0] * whs[(k0 + kk + 0) * 64 + o];
                a1 += hs[k0 + kk + 1] * whs[(k0 + kk + 1) * 64 + o];
                a2 += hs[k0 + kk + 2] * whs[(k0 + kk + 2) * 64 + o];
                a3 += hs[k0 + kk + 3] * whs[(k0 + kk + 3) * 64 + o];
            }
            psum[seg][o] = (a0 + a1) + (a2 + a3);
            __syncthreads();
            if (seg == 0){
                float a = 0.f;
                #pragma unroll
                for (int r = 0; r < 8; ++r) a += psum[r][o];
                const float* y = Y + (q * NTc + t) * DYc;
                float z = bh[out];
                #pragma unroll
                for (int d = 0; d < DYc; ++d) z += y[d] * Wih[d * HRc + out];
                __hip_atomic_store(dst + out, fast_tanh(z + a), __ATOMIC_RELEASE, __HIP_MEMORY_SCOPE_AGENT);
            }
            __syncthreads();
        } else {
            if (seg == 0)
                __hip_atomic_store(dst + out, hs[out], __ATOMIC_RELEASE, __HIP_MEMORY_SCOPE_AGENT);
            __syncthreads();
        }
        if (tid == 0)
            __hip_atomic_fetch_add(cnt, 1, __ATOMIC_RELEASE, __HIP_MEMORY_SCOPE_AGENT);
    }
}

// ---- MFMA helpers (4x4 grid, used by w12) ----
#define MMGRID(aa, bb) {                                                       \
    _Pragma("unroll") for (int i_ = 0; i_ < 4; ++i_)                           \
        _Pragma("unroll") for (int j_ = 0; j_ < 4; ++j_)                       \
            acc[i_][j_] = __builtin_amdgcn_mfma_f32_16x16x32_bf16(aa[i_], bb[j_], acc[i_][j_], 0, 0, 0); }

// stage BK=32 (1 kt): 8 A-chunks + 8 B-chunks of 1 KB; wave w stages 4 chunks
__device__ __forceinline__ void stage32(const short* __restrict__ Ap, const short* __restrict__ Bp,
                                        short* As, short* Bs,
                                        int at0, int bt0, int s, int KTOT, int wave, int lane){
    #pragma unroll
    for (int c = 0; c < 4; ++c){
        int ci = wave * 4 + c;            // 0..15
        int half = ci >> 3;               // 0 = A, 1 = B
        int t    = ci & 7;
        const short* src = half ? (Bp + ((size_t)(bt0 + t) * KTOT + s) * 512 + lane * 8)
                                : (Ap + ((size_t)(at0 + t) * KTOT + s) * 512 + lane * 8);
        short* dst = (half ? Bs : As) + t * 512;
        gld_lds16(src, dst);
    }
}

// compute one stage (1 kt x 16 MFMA per wave) from LDS
#define STAGE_COMPUTE(As, Bs) {                                                       \
    bf16x8 af[4], bfr[4];                                                             \
    _Pragma("unroll") for (int i_ = 0; i_ < 4; ++i_)                                  \
        af[i_] = *(const bf16x8*)((As) + ((wm * 4 + i_) * 512) + lane * 8);           \
    _Pragma("unroll") for (int j_ = 0; j_ < 4; ++j_)                                  \
        bfr[j_] = *(const bf16x8*)((Bs) + ((wn * 4 + j_) * 512) + lane * 8);          \
    MMGRID(af, bfr); }

// ---------------- z2acc + w12 + cY (one dispatch; w12/cY latency hidden under z2acc) ----------------
// blocks [0,128):   w12 = Wx2bf @ Wb1midbf -> W12p (B-layout for gemm_big)
// blocks [128,160): cY += eY-chunk @ Wb1[513:1025]  (cY pre-init to bb1 in prep)
// blocks [160,672): z2acc split-K: Z2Bacc += eXb @ Wb1[1:513]
__global__ __launch_bounds__(256) void z2w12cy_kernel(
    const float* __restrict__ eXb, const float* __restrict__ Wb1,
    float* __restrict__ Z2Bacc,
    const short* __restrict__ Wx2a, const short* __restrict__ Wb1p,
    short* __restrict__ W12p,
    const float* __restrict__ hb0, float* __restrict__ cY){
    __shared__ __align__(16) short Asb[2][4096];
    __shared__ __align__(16) short Bsb[2][4096];
    int b = blockIdx.x, tid = threadIdx.x;
    if (b < 128){
        // ---- w12: 128x128 tiles, K=512 (S=16) ----
        const int KTOT = 16, S = 16;
        int bw = b;
        int wave = tid >> 6, lane = tid & 63;
        int wm = wave >> 1, wn = wave & 1;
        int bx = bw & 15, by = bw >> 4;
        int quad = lane >> 4, llo = lane & 15;
        f32x4 acc[4][4];
        #pragma unroll
        for (int i = 0; i < 4; ++i)
            #pragma unroll
            for (int j = 0; j < 4; ++j) acc[i][j] = (f32x4){0.f, 0.f, 0.f, 0.f};
        stage32(Wx2a, Wb1p, Asb[0], Bsb[0], by * 8, bx * 8, 0, KTOT, wave, lane);
        for (int s = 0; s < S; ++s){
            int buf = s & 1;
            __syncthreads();
            if (s + 1 < S)
                stage32(Wx2a, Wb1p, Asb[buf ^ 1], Bsb[buf ^ 1], by * 8, bx * 8, s + 1, KTOT, wave, lane);
            STAGE_COMPUTE(Asb[buf], Bsb[buf]);
        }
        // write W12[c][h] into gemm_big's B layout: chunk = [h>>8][c>>6][((h>>4)&15)*2 + ((c>>5)&1)],
        // lane = ((c>>3)&3)*16 + (h&15), elem = c&7
        #pragma unroll
        for (int j = 0; j < 4; ++j){
            int h = bx * 128 + wn * 64 + j * 16 + llo;
            #pragma unroll
            for (int i = 0; i < 4; ++i){
                #pragma unroll
                for (int r = 0; r < 4; ++r){
                    int c = by * 128 + wm * 64 + i * 16 + quad * 4 + r;
                    size_t idx = ((((size_t)(h >> 8) * 16 + (c >> 6)) * 32)
                                  + ((h >> 4) & 15) * 2 + ((c >> 5) & 1)) * 512
                               + (size_t)(((c >> 3) & 3) * 16 + (h & 15)) * 8 + (c & 7);
                    W12p[idx] = f2bf(acc[i][j][r]);
                }
            }
        }
    } else if (b < 160){
        // ---- cY partial: 32 blocks = 4 e-chunks x 8 h-chunks ----
        __shared__ float hs2[128];
        int bb = b - 128;
        int e0 = (bb >> 3) * 128, h = (bb & 7) * 256 + tid;
        if (tid < 128) hs2[tid] = hb0[e0 + tid];
        __syncthreads();
        float acc = 0.f;
        #pragma unroll 4
        for (int e = 0; e < 128; ++e)
            acc += hs2[e] * Wb1[(size_t)(1 + EXc + e0 + e) * HBc + h];
        atomicAdd(&cY[h], acc);
    } else {
        // ---- z2acc split-K ----
        __shared__ float exs[8 * 256];
        int bz = b - 160;
        int mg = bz & 31, hh = (bz >> 5) & 7, kq = bz >> 8;
        int m0 = mg * 8, h = hh * 256 + tid, k0 = kq * 256;
        #pragma unroll
        for (int l = 0; l < 8; ++l){
            int idx = tid + l * 256;
            exs[idx] = eXb[(size_t)(m0 + (idx >> 8)) * EXc + k0 + (idx & 255)];
        }
        __syncthreads();
        float acc[8] = {};
        #pragma unroll 4
        for (int kk = 0; kk < 256; ++kk){
            float wv = Wb1[(size_t)(1 + k0 + kk) * HBc + h];
            #pragma unroll
            for (int mm = 0; mm < 8; ++mm) acc[mm] += exs[mm * 256 + kk] * wv;
        }
        #pragma unroll
        for (int mm = 0; mm < 8; ++mm)
            atomicAdd(&Z2Bacc[(size_t)(m0 + mm) * HBc + h], acc[mm]);
    }
}

// ---------------- tb: TB = tanh(Z2Bacc + (tk+tau_m)*Wb1[0] + cY) ----------------
__global__ void tb_kernel(const float* __restrict__ Z2Bacc, const float* __restrict__ Wb1,
                          const float* __restrict__ cY, const float* __restrict__ times_t,
                          const float* __restrict__ times_tau, const int* kptr,
                          float* __restrict__ TB){
    int b = blockIdx.x, tid = threadIdx.x;
    int m = b >> 3, h = (b & 7) * 256 + tid;
    float tk = times_t[kptr[0]];
    size_t idx = (size_t)m * HBc + h;
    float z = Z2Bacc[idx] + (tk + times_tau[m]) * Wb1[h] + cY[h];
    TB[idx] = fast_tanh(z);
}

// ================== gemm_big: 256x256 tile, BK=64, 8-wave, 8-phase counted-vmcnt schedule ==================
// Dz2 = A1p(16384x1024) @ W12p(1024x2048), fused tanh-delta epilogue.
// Grid: FLAT 512 blocks with chunked XCD swizzle (round 3 showed the kernel is staging-delivery-bound
// at ~6 TB/s aggregate with A streamed 8x from L3; m201 sustains ~13.5 TB/s when slabs are L2-resident).
// Mapping: hardware assigns XCD = id%8 (round-robin); we invert so XCD x executes work chunk
// w in [64x, 64x+64) in dispatch order: w = (id%8)*64 + id/8; bm = (w>>6)*8 + ((w&63)>>3); bn = w&7.
// Per XCD per 32-CU round: working set = 4 A-slabs (2 MB) + 8 B-slabs (4 MB), all co-resident blocks
// staging the same kt in the same phase window -> L2-hit staging. Off-XCD traffic ~290 MB -> ~96 MB.
// 512 threads (8 waves: wm=wave>>2, wn=wave&3), per-wave 128x64 output (8x4 16x16 frags).
// LDS: As[2][32KB] + Bs[2][32KB] = 128 KiB (1 block/CU). Operands pre-packed in MFMA fragment order
// -> every ds_read_b128 is the contiguous lane*16B pattern (0 bank conflicts), staging is linear.
//
// Stage schedule (tile T computed ph1-4 in buf0, T+1 ph5-8 in buf1; per phase 1 half-tile staged):
//   ph1: T+1.A0   ph2: T+1.A1   ph3: T+2.B0   ph4: T+2.B1 + vmcnt(4)
//   ph5: T+2.A0   ph6: T+2.A1   ph7: T+3.B0   ph8: T+3.B1 + vmcnt(4)
// vmcnt(4) at ph4/ph8 leaves exactly the last 2 half-tile stages in flight -> next tile resident.
__device__ __forceinline__ void stage_half(const short* __restrict__ base, short* lbase,
                                           int wave, int lane){
    const short* s = base + (size_t)(wave * 2) * 512 + lane * 8;
    short* d = lbase + (wave * 2) * 512;
    gld_lds16(s, d);
    gld_lds16(s + 512, d + 512);
}

__global__ __launch_bounds__(512, 2) void gemm_big(
    const short* __restrict__ Ap, const short* __restrict__ Bp,
    const float* __restrict__ TB, const float* __restrict__ wrow,
    float* __restrict__ dacc){
    __shared__ __align__(16) short As[2][16384];
    __shared__ __align__(16) short Bs[2][16384];
    __shared__ float redn[256];
    int tid = threadIdx.x;
    int wave = tid >> 6, lane = tid & 63;
    int wm = wave >> 2, wn = wave & 3;
    // chunked XCD swizzle (bijective: 512 % 8 == 0)
    int id = blockIdx.x;
    int w  = (id & 7) * 64 + (id >> 3);
    int bm = ((w >> 6) << 3) + ((w & 63) >> 3);
    int bn = w & 7;
    int quad = lane >> 4, llo = lane & 15;
    const short* Ab = Ap + (size_t)bm * 16 * 32 * 512;   // 256-row slab: 16 ktiles x 32 chunks x 1KB
    const short* Bb = Bp + (size_t)bn * 16 * 32 * 512;   // 256-col slab

    f32x4 acc[8][4];
    #pragma unroll
    for (int i = 0; i < 8; ++i)
        #pragma unroll
        for (int j = 0; j < 4; ++j) acc[i][j] = (f32x4){0.f, 0.f, 0.f, 0.f};

    bf16x8 af[4][2];   // current m-quad A frags [i][kk]
    bf16x8 bfr[4][2];  // all 4 n frags [nt_local][kk], held across the tile

#define BARX() __builtin_amdgcn_s_barrier()
#define GATE4() asm volatile("s_waitcnt vmcnt(4)" ::: "memory")
#define GATE0() asm volatile("s_waitcnt vmcnt(0)" ::: "memory")
#define STAGE_A(kt, h, buf) stage_half(Ab + ((size_t)(kt) * 32 + (h) * 16) * 512, &As[buf][(h) * 16 * 512], wave, lane)
#define STAGE_B(kt, h, buf) stage_half(Bb + ((size_t)(kt) * 32 + (h) * 16) * 512, &Bs[buf][(h) * 16 * 512], wave, lane)
#define RD_A(buf, ib) { _Pragma("unroll") for (int i_ = 0; i_ < 4; ++i_)                                   \
        _Pragma("unroll") for (int k_ = 0; k_ < 2; ++k_)                                                   \
            af[i_][k_] = *(const bf16x8*)&As[buf][(((wm * 8 + (ib) + i_) * 2 + k_) * 512) + lane * 8]; }
#define RD_B(buf, jb) { _Pragma("unroll") for (int j_ = 0; j_ < 2; ++j_)                                   \
        _Pragma("unroll") for (int k_ = 0; k_ < 2; ++k_)                                                   \
            bfr[(jb) + j_][k_] = *(const bf16x8*)&Bs[buf][(((wn * 4 + (jb) + j_) * 2 + k_) * 512) + lane * 8]; }
#define MFMA16(mb, nb) { _Pragma("unroll") for (int k_ = 0; k_ < 2; ++k_)                                  \
        _Pragma("unroll") for (int i_ = 0; i_ < 4; ++i_)                                                   \
        _Pragma("unroll") for (int j_ = 0; j_ < 2; ++j_)                                                   \
            acc[(mb) + i_][(nb) + j_] = __builtin_amdgcn_mfma_f32_16x16x32_bf16(                           \
                af[i_][k_], bfr[(nb) + j_][k_], acc[(mb) + i_][(nb) + j_], 0, 0, 0); }
#define PH(reads, stage, mfma, gate) do {                                                                  \
        reads; stage;                                                                                      \
        BARX();                                                                                            \
        __builtin_amdgcn_s_setprio(1); mfma; __builtin_amdgcn_s_setprio(0);                                \
        gate;                                                                                              \
        BARX(); } while (0)

    // prologue: tile0 (B then A) + tile1 B; vmcnt(4) -> tile0 fully resident, 1.B0/1.B1 in flight
    STAGE_B(0, 0, 0); STAGE_B(0, 1, 0);
    STAGE_A(0, 0, 0); STAGE_A(0, 1, 0);
    STAGE_B(1, 0, 1); STAGE_B(1, 1, 1);
    GATE4();
    BARX();

    for (int T = 0; T < 14; T += 2){
        PH(RD_A(0, 0); RD_B(0, 0), STAGE_A(T + 1, 0, 1), MFMA16(0, 0), );
        PH(RD_B(0, 2),             STAGE_A(T + 1, 1, 1), MFMA16(0, 2), );
        PH(RD_A(0, 4),             STAGE_B(T + 2, 0, 0), MFMA16(4, 0), );
        PH(                      , STAGE_B(T + 2, 1, 0), MFMA16(4, 2), GATE4());
        PH(RD_A(1, 0); RD_B(1, 0), STAGE_A(T + 2, 0, 0), MFMA16(0, 0), );
        PH(RD_B(1, 2),             STAGE_A(T + 2, 1, 0), MFMA16(0, 2), );
        PH(RD_A(1, 4),             STAGE_B(T + 3, 0, 1), MFMA16(4, 0), );
        PH(                      , STAGE_B(T + 3, 1, 1), MFMA16(4, 2), GATE4());
    }
    // peeled final iteration: T=14 (tiles 14,15); only 15.A0/A1 remain to stage
    PH(RD_A(0, 0); RD_B(0, 0), STAGE_A(15, 0, 1), MFMA16(0, 0), );
    PH(RD_B(0, 2),             STAGE_A(15, 1, 1), MFMA16(0, 2), );
    PH(RD_A(0, 4),           ,                    MFMA16(4, 0), );
    PH(                      , ,                  MFMA16(4, 2), GATE0());
    PH(RD_A(1, 0); RD_B(1, 0), ,                  MFMA16(0, 0), );
    PH(RD_B(1, 2),             ,                  MFMA16(0, 2), );
    PH(RD_A(1, 4),             ,                  MFMA16(4, 0), );
    PH(                      , ,                  MFMA16(4, 2), );

#undef PH
#undef MFMA16
#undef RD_B
#undef RD_A
#undef STAGE_B
#undef STAGE_A
#undef GATE0
#undef GATE4
#undef BARX

    // fused epilogue: tanh(zb+dz)-tanh(zb) = tdz*(1-tb^2)/(1+tb*tdz), weighted by wrow, reduce over m
    int nj[4];
    #pragma unroll
    for (int j = 0; j < 4; ++j) nj[j] = bn * 256 + wn * 64 + j * 16 + llo;
    float part[4] = {};
    #pragma unroll
    for (int i = 0; i < 8; ++i){
        #pragma unroll
        for (int r = 0; r < 4; ++r){
            int m = bm * 256 + wm * 128 + i * 16 + quad * 4 + r;
            float wr = wrow[m];
            const float* trow = TB + (size_t)(m & 255) * HBc;
            #pragma unroll
            for (int j = 0; j < 4; ++j){
                float tb  = trow[nj[j]];
                float tdz = fast_tanh(acc[i][j][r]);
                float num = tdz * (1.0f - tb * tb);
                float den = 1.0f + tb * tdz;
                part[j] += wr * num * __builtin_amdgcn_rcpf(den);
            }
        }
    }
    #pragma unroll
    for (int j = 0; j < 4; ++j){
        part[j] += __shfl_xor(part[j], 16);
        part[j] += __shfl_xor(part[j], 32);
    }
    if (tid < 256) redn[tid] = 0.f;
    __syncthreads();
    if (quad == 0){
        #pragma unroll
        for (int j = 0; j < 4; ++j)
            atomicAdd(&redn[wn * 64 + j * 16 + llo], part[j]);
    }
    __syncthreads();
    if (tid < 256) atomicAdd(&dacc[bn * 256 + tid], redn[tid]);
}

// ---------------- si = dacc @ Wb2, split over 8 blocks (out pre-zeroed in prep) ----------------
__global__ void out_kernel(const float* __restrict__ dacc, const float* __restrict__ Wb2,
                           float* __restrict__ out){
    __shared__ float red[4][64];
    int tid = threadIdx.x;
    int g = tid & 63, seg = tid >> 6;
    int h0 = blockIdx.x * 256 + seg * 64;
    float s = 0.f;
    #pragma unroll 8
    for (int hh = 0; hh < 64; ++hh)
        s += dacc[h0 + hh] * Wb2[(size_t)(h0 + hh) * GOUTc + g];
    red[seg][g] = s;
    __syncthreads();
    if (tid < 64)
        atomicAdd(&out[tid], red[0][tid] + red[1][tid] + red[2][tid] + red[3][tid]);
}

extern "C" void kernel_launch(void* const* d_in, const int* in_sizes, int n_in,
                              void* d_out, int out_size, void* d_ws, size_t ws_size,
                              hipStream_t stream){
    const float* X         = (const float*)d_in[0];
    const float* Y         = (const float*)d_in[1];
    const float* R         = (const float*)d_in[2];
    const float* stoich    = (const float*)d_in[3];
    const float* times_t   = (const float*)d_in[4];
    const float* times_tau = (const float*)d_in[5];
    const float* Wx1 = (const float*)d_in[6];
    const float* bx1 = (const float*)d_in[7];
    const float* Wx2 = (const float*)d_in[8];
    const float* bx2 = (const float*)d_in[9];
    const float* Wih = (const float*)d_in[10];
    const float* Whh = (const float*)d_in[11];
    const float* bh  = (const float*)d_in[12];
    const float* Wb1 = (const float*)d_in[13];
    const float* bb1 = (const float*)d_in[14];
    const float* Wb2 = (const float*)d_in[15];
    // d_in[16] = bb2: cancels in (nn_disp - nn), unused
    const int* kp  = (const int*)d_in[17];
    const int* kpp = (const int*)d_in[18];
    const int* qp  = (const int*)d_in[19];
    const int* qpp = (const int*)d_in[20];
    float* out = (float*)d_out;

    float* ws     = (float*)d_ws;
    float* hb0    = ws;                        // 512
    float* hb1    = ws + 512;                  // 512
    float* cY     = ws + 1024;                 // 2048
    float* dacc   = ws + 3072;                 // 2048
    float* wrow   = ws + 5120;                 // 64*256 = 16384
    float* SW     = ws + 21504;                // 64*1024 = 65536
    float* XW     = ws + 87040;                // 256*1024 = 262144
    float* T1     = ws + 349184;               // 256*1024 = 262144
    float* eXb    = ws + 611328;               // 256*512 = 131072
    float* TB     = ws + 742400;               // 256*2048 = 524288
    float* Z2Bacc = ws + 1266688;              // 256*2048 = 524288
    short* A1p    = (short*)(ws + 1790976);    // 16384*1024 bf16 = 8,388,608 float slots
    short* Wx2a   = (short*)(ws + 10179584);   // 1024*512 bf16 = 262,144 float slots
    short* Wb1p   = (short*)(ws + 10441728);   // 512*2048 bf16 = 524,288 float slots
    short* W12p   = (short*)(ws + 10966016);   // 1024*2048 bf16 = 1,048,576 float slots
    int*   cnt    = (int*)(ws + 12014592);     // 1 int (RNN step counter)
    // total ws use: ~12.0M floats = 48.1 MB

    prep_kernel   <<<4673, 256, 0, stream>>>(stoich, Wx1, Wx2, Wb1, X, R, bx1, bx2, bb1, kpp, qpp,
                                             SW, Wx2a, Wb1p, XW, T1, wrow, hb0, dacc, out,
                                             eXb, Z2Bacc, cY, cnt);
    act_ex_kernel <<<8704, 256, 0, stream>>>(XW, T1, SW, A1p, Wx2, eXb);
    rnn_kernel    <<<8,    512, 0, stream>>>(Y, Wih, Whh, bh, kp, qp, hb0, hb1, cnt);
    z2w12cy_kernel<<<672,  256, 0, stream>>>(eXb, Wb1, Z2Bacc, Wx2a, Wb1p, W12p, hb0, cY);
    tb_kernel     <<<2048, 256, 0, stream>>>(Z2Bacc, Wb1, cY, times_t, times_tau, kp, TB);
    gemm_big      <<<dim3(512), 512, 0, stream>>>(A1p, W12p, TB, wrow, dacc);
    out_kernel    <<<8,    256, 0, stream>>>(dacc, Wb2, out);
}